// Round 16
// baseline (6355.606 us; speedup 1.0000x reference)
//
#include <hip/hip_runtime.h>
#include <hip/hip_bf16.h>
#include <cstdint>
#include <cstddef>

#define T_SEQ   512
#define BATCH   8
#define BT      4096
#define DMODEL  1024
#define NHEAD   16
#define HSZ     64
#define NLAYER  8
#define DFF     4096
#define VOCAB   32000
#define EPS     1e-6f
#define NEG_SLOPE 0.1f
#define QLD     3072
#define MSCALE  2048.0f
#define MINV    (1.0f / 2048.0f)

typedef _Float16 f16;
typedef __attribute__((ext_vector_type(8))) _Float16 half8;
typedef __attribute__((ext_vector_type(4))) _Float16 half4;
typedef __attribute__((ext_vector_type(4))) float f32x4;

#define AS1 __attribute__((address_space(1)))
#define AS3 __attribute__((address_space(3)))

#define WAIT_BAR(N) asm volatile("s_waitcnt vmcnt(" #N ")\ns_barrier" ::: "memory")
#define LGKM_BAR()  asm volatile("s_waitcnt lgkmcnt(0)\ns_barrier" ::: "memory")

// ---------------------------------------------------------------------------
__global__ void embed_kernel(const int* __restrict__ idx,
                             const float* __restrict__ tok,
                             const float* __restrict__ pos,
                             float* __restrict__ x) {
    int bt  = blockIdx.x;
    int tid = threadIdx.x;
    int token = idx[bt];
    int t = bt & (T_SEQ - 1);
    float4 a = reinterpret_cast<const float4*>(tok + (size_t)token * DMODEL)[tid];
    float4 p = reinterpret_cast<const float4*>(pos + (size_t)t * DMODEL)[tid];
    reinterpret_cast<float4*>(x + (size_t)bt * DMODEL)[tid] =
        make_float4(a.x + p.x, a.y + p.y, a.z + p.z, a.w + p.w);
}

// ---------------------------------------------------------------------------
__device__ __forceinline__ void split2h(float v, f16& h, f16& m) {
    f16 hh = (f16)v;
    float hf = (float)hh;
    if (fabsf(hf) < 6.103515625e-05f) { hh = (f16)0.0f; hf = 0.0f; }
    h = hh;
    m = (f16)((v - hf) * MSCALE);
}

// ---------------------------------------------------------------------------
__global__ void rms_split(const float* __restrict__ x,
                          const float* __restrict__ w,
                          f16* __restrict__ out, size_t planeStride) {
    int row = blockIdx.x;
    int tid = threadIdx.x;
    float4 v = reinterpret_cast<const float4*>(x + (size_t)row * DMODEL)[tid];
    float ss = v.x * v.x + v.y * v.y + v.z * v.z + v.w * v.w;
#pragma unroll
    for (int off = 32; off > 0; off >>= 1) ss += __shfl_xor(ss, off);
    __shared__ float wsum[4];
    if ((tid & 63) == 0) wsum[tid >> 6] = ss;
    __syncthreads();
    float tot = wsum[0] + wsum[1] + wsum[2] + wsum[3];
    float scale = rsqrtf(tot * (1.0f / DMODEL) + EPS);
    float4 wv = reinterpret_cast<const float4*>(w)[tid];
    float o[4] = {v.x * scale * wv.x, v.y * scale * wv.y,
                  v.z * scale * wv.z, v.w * scale * wv.w};
    size_t base = (size_t)row * DMODEL + tid * 4;
#pragma unroll
    for (int j = 0; j < 4; ++j) {
        f16 h, m;
        split2h(o[j], h, m);
        out[base + j] = h;
        out[planeStride + base + j] = m;
    }
}

// ---------------------------------------------------------------------------
__global__ __launch_bounds__(256)
void transpose_split(const float* __restrict__ in, f16* __restrict__ out,
                     size_t planeStride, int R, int C,
                     long izs, long ozi) {
    int z = blockIdx.z;
    in  += (size_t)z * izs;
    out += (size_t)z * ozi;
    __shared__ float tile[32][33];
    int r0 = blockIdx.y << 5, c0 = blockIdx.x << 5;
    int tx = threadIdx.x & 31, ty = threadIdx.x >> 5;
#pragma unroll
    for (int i = 0; i < 4; ++i) {
        int r = ty + (i << 3);
        tile[r][tx] = in[(size_t)(r0 + r) * C + c0 + tx];
    }
    __syncthreads();
#pragma unroll
    for (int i = 0; i < 4; ++i) {
        int c = ty + (i << 3);
        float v = tile[tx][c];
        size_t o = (size_t)(c0 + c) * R + r0 + tx;
        f16 h, m;
        split2h(v, h, m);
        out[o] = h;
        out[planeStride + o] = m;
    }
}

// concat per-layer qkv bias into (L, 3072) f32
__global__ void cat_bias(const float* __restrict__ bq, const float* __restrict__ bk,
                         const float* __restrict__ bv, float* __restrict__ cb) {
    int i = blockIdx.x * 256 + threadIdx.x;
    int l = i / QLD, r = i - l * QLD;
    const float* src = (r < 1024) ? bq : ((r < 2048) ? bk : bv);
    cb[i] = src[l * 1024 + (r & 1023)];
}

// ---------------------------------------------------------------------------
// f16 split-GEMM: 3 passes, 2 accumulators. r16: FULL double-buffer on both
// operands (64KB LDS, 2 blk/CU) + counted-vmcnt -> 2 barriers/step:
//   top:  STAGE(A+B -> buf^1); WAIT_BAR(4)   [drains step-t loads; t+1's 4
//         loads get a FULL step of latency cover, not just the MFMA block]
//   body: frag reads + MFMA from buf[cur]    [no mid barrier]
//   end:  LGKM_BAR                            [reads done before t+1's STAGE
//                                              overwrites buf[cur]]
// Per-element accumulation order identical to r13/r15 (absmax canary).
// VOUT: QKV blocks with n0 >= 2048 write transposed V planes directly.
template <bool LRELU, bool SPLITOUT, bool VOUT>
__global__ __launch_bounds__(512, 4)
void gemm_f16(const f16* __restrict__ A, size_t aPS,
              const f16* __restrict__ Bt, size_t bPS,
              const float* __restrict__ bias,
              const float* __restrict__ resid,
              float* __restrict__ C, f16* __restrict__ Cp, size_t cPS,
              f16* __restrict__ vTp, size_t vPS,
              int N, int K) {
    __shared__ f16 As[2][2 * 4096];
    __shared__ f16 Bs[2][2 * 4096];

    int chunk = gridDim.x >> 3;
    int bid = blockIdx.x;
    int sw = (bid & 7) * chunk + (bid >> 3);
    int m0 = (sw & 31) << 7;
    int n0 = (sw >> 5) << 7;

    const int tid  = threadIdx.x;
    const int lane = tid & 63;
    const int wid  = tid >> 6;

    const int ssk = (((tid & 3) ^ ((tid >> 3) & 3)) << 3);
    const size_t offA = (size_t)(m0 + (tid >> 2)) * K + ssk;
    const size_t offB = (size_t)(n0 + (tid >> 2)) * K + ssk;
    const int ldst = wid * 512;

    f32x4 accH[4][2], accM[4][2];
#pragma unroll
    for (int i = 0; i < 4; ++i)
#pragma unroll
        for (int j = 0; j < 2; ++j) {
            accH[i][j] = (f32x4){0.f, 0.f, 0.f, 0.f};
            accM[i][j] = (f32x4){0.f, 0.f, 0.f, 0.f};
        }

    const int wr = wid >> 2, wc = wid & 3;
    const int fm = lane & 15;
    const int rslot = (((lane >> 4) ^ ((lane >> 1) & 3)) & 3) << 3;
    const int foffA0 = (wr * 64 + fm) * 32 + rslot;
    const int foffB0 = (wc * 32 + fm) * 32 + rslot;

    auto STAGE = [&](int buf, int k0) {
#pragma unroll
        for (int pp = 0; pp < 2; ++pp)
            __builtin_amdgcn_global_load_lds(
                (const AS1 void*)(A + pp * aPS + offA + k0),
                (AS3 void*)(&As[buf][pp * 4096 + ldst]), 16, 0, 0);
#pragma unroll
        for (int pp = 0; pp < 2; ++pp)
            __builtin_amdgcn_global_load_lds(
                (const AS1 void*)(Bt + pp * bPS + offB + k0),
                (AS3 void*)(&Bs[buf][pp * 4096 + ldst]), 16, 0, 0);
    };

    const int nt = K >> 5;
    STAGE(0, 0);
    int cur = 0;
    for (int t = 0; t < nt; ++t) {
        if (t + 1 < nt) {
            STAGE(cur ^ 1, (t + 1) << 5);
            WAIT_BAR(4);
        } else {
            WAIT_BAR(0);
        }

        half8 bh[2], bm[2];
#pragma unroll
        for (int j = 0; j < 2; ++j) {
            bh[j] = *(const half8*)(&Bs[cur][foffB0 + j * 512]);
            bm[j] = *(const half8*)(&Bs[cur][4096 + foffB0 + j * 512]);
        }
#pragma unroll
        for (int i = 0; i < 4; ++i) {
            half8 ah = *(const half8*)(&As[cur][foffA0 + i * 512]);
            half8 am = *(const half8*)(&As[cur][4096 + foffA0 + i * 512]);
#pragma unroll
            for (int j = 0; j < 2; ++j) {
                accM[i][j] = __builtin_amdgcn_mfma_f32_16x16x32_f16(
                    am, bh[j], accM[i][j], 0, 0, 0);
                accM[i][j] = __builtin_amdgcn_mfma_f32_16x16x32_f16(
                    ah, bm[j], accM[i][j], 0, 0, 0);
                accH[i][j] = __builtin_amdgcn_mfma_f32_16x16x32_f16(
                    ah, bh[j], accH[i][j], 0, 0, 0);
            }
        }
        LGKM_BAR();     // all waves' ds_reads of buf[cur] complete before the
                        // next-top STAGE overwrites it
        cur ^= 1;
    }

    const bool vblock = VOUT && (n0 >= 2048);
#pragma unroll
    for (int i = 0; i < 4; ++i) {
        int mbase = m0 + wr * 64 + i * 16 + ((lane >> 4) << 2);
#pragma unroll
        for (int j = 0; j < 2; ++j) {
            int n = n0 + wc * 32 + j * 16 + fm;
            float bv = bias[n];
            if (vblock) {
                half4 ph4, pm4;
#pragma unroll
                for (int rr = 0; rr < 4; ++rr) {
                    float v = accH[i][j][rr] + accM[i][j][rr] * MINV + bv;
                    f16 hh, mm;
                    split2h(v, hh, mm);
                    ph4[rr] = hh;
                    pm4[rr] = mm;
                }
                int nn = n - 2048;
                int bb = mbase >> 9, tt = mbase & 511;
                size_t vo = (((size_t)(bb * 16 + (nn >> 6)) * 64 + (nn & 63)) << 9) + tt;
                *(half4*)(vTp + vo) = ph4;
                *(half4*)(vTp + vPS + vo) = pm4;
            } else {
#pragma unroll
                for (int rr = 0; rr < 4; ++rr) {
                    int m = mbase + rr;
                    float v = accH[i][j][rr] + accM[i][j][rr] * MINV + bv;
                    if (LRELU) v = (v >= 0.f) ? v : NEG_SLOPE * v;
                    size_t o = (size_t)m * N + n;
                    if (SPLITOUT) {
                        f16 h, mm;
                        split2h(v, h, mm);
                        Cp[o] = h;
                        Cp[cPS + o] = mm;
                    } else {
                        if (resid) v += resid[o];
                        C[o] = v;
                    }
                }
            }
        }
    }
}

// ---------------------------------------------------------------------------
// Single-pass plain-f16 vocab GEMM, full dbuf both operands (48KB LDS),
// 2 barriers/step, NT stores for the write-once C stream.
__global__ __launch_bounds__(512, 4)
void gemm_f16_1p(const f16* __restrict__ A,
                 const f16* __restrict__ Bt,
                 const float* __restrict__ bias,
                 float* __restrict__ C, int N, int K) {
    __shared__ f16 As[2][4096];
    __shared__ f16 Bs[2][4096];

    int chunk = gridDim.x >> 3;
    int bid = blockIdx.x;
    int sw = (bid & 7) * chunk + (bid >> 3);
    int m0 = (sw & 31) << 7;
    int n0 = (sw >> 5) << 7;

    const int tid  = threadIdx.x;
    const int lane = tid & 63;
    const int wid  = tid >> 6;

    const int ssk = (((tid & 3) ^ ((tid >> 3) & 3)) << 3);
    const size_t offA = (size_t)(m0 + (tid >> 2)) * K + ssk;
    const size_t offB = (size_t)(n0 + (tid >> 2)) * K + ssk;
    const int ldst = wid * 512;

    f32x4 acc[4][2];
#pragma unroll
    for (int i = 0; i < 4; ++i)
#pragma unroll
        for (int j = 0; j < 2; ++j) acc[i][j] = (f32x4){0.f, 0.f, 0.f, 0.f};

    const int wr = wid >> 2, wc = wid & 3;
    const int fm = lane & 15;
    const int rslot = (((lane >> 4) ^ ((lane >> 1) & 3)) & 3) << 3;
    const int foffA0 = (wr * 64 + fm) * 32 + rslot;
    const int foffB0 = (wc * 32 + fm) * 32 + rslot;

    auto STAGE = [&](int buf, int k0) {
        __builtin_amdgcn_global_load_lds((const AS1 void*)(A + offA + k0),
                                         (AS3 void*)(&As[buf][ldst]), 16, 0, 0);
        __builtin_amdgcn_global_load_lds((const AS1 void*)(Bt + offB + k0),
                                         (AS3 void*)(&Bs[buf][ldst]), 16, 0, 0);
    };

    const int nt = K >> 5;
    STAGE(0, 0);
    int cur = 0;
    for (int t = 0; t < nt; ++t) {
        if (t + 1 < nt) {
            STAGE(cur ^ 1, (t + 1) << 5);
            WAIT_BAR(2);
        } else {
            WAIT_BAR(0);
        }

        half8 bh[2];
#pragma unroll
        for (int j = 0; j < 2; ++j)
            bh[j] = *(const half8*)(&Bs[cur][foffB0 + j * 512]);
#pragma unroll
        for (int i = 0; i < 4; ++i) {
            half8 ah = *(const half8*)(&As[cur][foffA0 + i * 512]);
#pragma unroll
            for (int j = 0; j < 2; ++j)
                acc[i][j] = __builtin_amdgcn_mfma_f32_16x16x32_f16(
                    ah, bh[j], acc[i][j], 0, 0, 0);
        }
        LGKM_BAR();
        cur ^= 1;
    }

#pragma unroll
    for (int i = 0; i < 4; ++i) {
        int mbase = m0 + wr * 64 + i * 16 + ((lane >> 4) << 2);
#pragma unroll
        for (int j = 0; j < 2; ++j) {
            int n = n0 + wc * 32 + j * 16 + fm;
            float bv = bias[n];
#pragma unroll
            for (int rr = 0; rr < 4; ++rr) {
                int m = mbase + rr;
                __builtin_nontemporal_store(acc[i][j][rr] + bv,
                                            C + (size_t)m * N + n);
            }
        }
    }
}

// ---------------------------------------------------------------------------
// MFMA flash attention, split-f16 3-pass (r14-identical, canary-validated).
template <int CAUSAL>
__global__ __launch_bounds__(256)
void attn_mfma(const f16* __restrict__ qkvp, size_t QPS,
               const f16* __restrict__ vT, size_t VPS,
               f16* __restrict__ outp, size_t OPS) {
    __shared__ f16 lds[24576];
    const int tid  = threadIdx.x;
    const int lane = tid & 63;
    const int wid  = tid >> 6;
    const int tl   = lane & 15;
    const int g    = lane >> 4;

    int bh = blockIdx.y;
    int b = bh >> 4, h = bh & 15;
    int t0 = blockIdx.x << 6;
    const int PB = 16384 + wid * 2048;

    half8 Qh[2], Qm[2];
    {
        const f16* qb = qkvp + (size_t)(b * 512 + t0 + wid * 16 + tl) * 3072
                        + h * 64 + (g << 3);
        Qh[0] = *(const half8*)(qb);
        Qh[1] = *(const half8*)(qb + 32);
        Qm[0] = *(const half8*)(qb + QPS);
        Qm[1] = *(const half8*)(qb + QPS + 32);
    }

    f32x4 oH[4], oM[4];
#pragma unroll
    for (int en = 0; en < 4; ++en) {
        oH[en] = (f32x4){0.f, 0.f, 0.f, 0.f};
        oM[en] = (f32x4){0.f, 0.f, 0.f, 0.f};
    }
    float m_run = -INFINITY, l_run = 0.f;

    auto STAGE1 = [&](int ldsOff, const f16* srcBase, int rowStride) {
#pragma unroll
        for (int it = 0; it < 2; ++it) {
            int r  = (tid >> 3) + it * 32;
            int cp = (tid & 7) ^ (r & 7);
            __builtin_amdgcn_global_load_lds(
                (const AS1 void*)(srcBase + (size_t)r * rowStride + cp * 8),
                (AS3 void*)(lds + ldsOff + (it * 32 + wid * 8) * 64), 16, 0, 0);
        }
    };

    const int NT = CAUSAL ? (blockIdx.x + 1) : (T_SEQ / 64);
    for (int st = 0; st < NT; ++st) {
        int s0 = st << 6;
        {
            const f16* kS = qkvp + (size_t)(b * 512 + s0) * 3072 + 1024 + h * 64;
            const f16* vS = vT + ((size_t)(bh * 64) << 9) + s0;
            STAGE1(0,     kS, 3072);
            STAGE1(4096,  kS + QPS, 3072);
            STAGE1(8192,  vS, 512);
            STAGE1(12288, vS + VPS, 512);
        }
        __syncthreads();

        f32x4 sH[4], sM[4];
#pragma unroll
        for (int sm = 0; sm < 4; ++sm) {
            sH[sm] = (f32x4){0.f, 0.f, 0.f, 0.f};
            sM[sm] = (f32x4){0.f, 0.f, 0.f, 0.f};
        }
#pragma unroll
        for (int sm = 0; sm < 4; ++sm) {
            int sl = sm * 16 + tl;
#pragma unroll
            for (int kf = 0; kf < 2; ++kf) {
                int sp = ((kf * 4 + g) ^ (sl & 7)) << 3;
                half8 kh = *(const half8*)(lds + sl * 64 + sp);
                half8 km = *(const half8*)(lds + 4096 + sl * 64 + sp);
                sM[sm] = __builtin_amdgcn_mfma_f32_16x16x32_f16(km, Qh[kf], sM[sm], 0, 0, 0);
                sM[sm] = __builtin_amdgcn_mfma_f32_16x16x32_f16(kh, Qm[kf], sM[sm], 0, 0, 0);
                sH[sm] = __builtin_amdgcn_mfma_f32_16x16x32_f16(kh, Qh[kf], sH[sm], 0, 0, 0);
            }
        }

        float sv[4][4];
#pragma unroll
        for (int sm = 0; sm < 4; ++sm)
#pragma unroll
            for (int rr = 0; rr < 4; ++rr) {
                float v = (sH[sm][rr] + sM[sm][rr] * MINV) * 8.0f;
                if (CAUSAL && st == NT - 1) {
                    int sg = s0 + sm * 16 + (g << 2) + rr;
                    int tg = t0 + wid * 16 + tl;
                    if (sg > tg) v = -INFINITY;
                }
                sv[sm][rr] = v;
            }
        float rmax = -INFINITY;
#pragma unroll
        for (int sm = 0; sm < 4; ++sm)
#pragma unroll
            for (int rr = 0; rr < 4; ++rr) rmax = fmaxf(rmax, sv[sm][rr]);
        rmax = fmaxf(rmax, __shfl_xor(rmax, 16));
        rmax = fmaxf(rmax, __shfl_xor(rmax, 32));
        float mn = fmaxf(m_run, rmax);
        float fsc = __expf(m_run - mn);
        float rs = 0.f;
#pragma unroll
        for (int sm = 0; sm < 4; ++sm)
#pragma unroll
            for (int rr = 0; rr < 4; ++rr) {
                float p = __expf(sv[sm][rr] - mn);
                sv[sm][rr] = p;
                rs += p;
            }
        rs += __shfl_xor(rs, 16);
        rs += __shfl_xor(rs, 32);
        l_run = l_run * fsc + rs;
        m_run = mn;
#pragma unroll
        for (int en = 0; en < 4; ++en)
#pragma unroll
            for (int rr = 0; rr < 4; ++rr) {
                oH[en][rr] *= fsc;
                oM[en][rr] *= fsc;
            }

#pragma unroll
        for (int sm = 0; sm < 4; ++sm) {
            half4 ph4, pm4;
#pragma unroll
            for (int rr = 0; rr < 4; ++rr) {
                f16 hh, mm;
                split2h(sv[sm][rr], hh, mm);
                ph4[rr] = hh;
                pm4[rr] = mm;
            }
            int sbase = sm * 16 + (g << 2);
            int sp = (sbase >> 3) ^ (tl & 7);
            int eo = PB + tl * 64 + sp * 8 + (sbase & 7);
            *(half4*)(lds + eo) = ph4;
            *(half4*)(lds + eo + 1024) = pm4;
        }
        asm volatile("s_waitcnt lgkmcnt(0)" ::: "memory");
        __builtin_amdgcn_sched_barrier(0);

        half8 Ph[2], Pm[2];
#pragma unroll
        for (int kf = 0; kf < 2; ++kf) {
            int sp = ((kf * 4 + g) ^ (tl & 7)) << 3;
            Ph[kf] = *(const half8*)(lds + PB + tl * 64 + sp);
            Pm[kf] = *(const half8*)(lds + PB + 1024 + tl * 64 + sp);
        }
#pragma unroll
        for (int en = 0; en < 4; ++en) {
            int el = en * 16 + tl;
#pragma unroll
            for (int kf = 0; kf < 2; ++kf) {
                int sp = ((kf * 4 + g) ^ (el & 7)) << 3;
                half8 vh = *(const half8*)(lds + 8192 + el * 64 + sp);
                half8 vm = *(const half8*)(lds + 12288 + el * 64 + sp);
                oM[en] = __builtin_amdgcn_mfma_f32_16x16x32_f16(vm, Ph[kf], oM[en], 0, 0, 0);
                oM[en] = __builtin_amdgcn_mfma_f32_16x16x32_f16(vh, Pm[kf], oM[en], 0, 0, 0);
                oH[en] = __builtin_amdgcn_mfma_f32_16x16x32_f16(vh, Ph[kf], oH[en], 0, 0, 0);
            }
        }
        __syncthreads();
    }

    float inv = 1.f / l_run;
    size_t obase = (size_t)(b * 512 + t0 + wid * 16 + tl) * 1024 + h * 64;
#pragma unroll
    for (int en = 0; en < 4; ++en) {
        half4 ph4, pm4;
#pragma unroll
        for (int rr = 0; rr < 4; ++rr) {
            float v = (oH[en][rr] + oM[en][rr] * MINV) * inv;
            f16 hh, mm;
            split2h(v, hh, mm);
            ph4[rr] = hh;
            pm4[rr] = mm;
        }
        size_t oc = obase + en * 16 + (g << 2);
        *(half4*)(outp + oc) = ph4;
        *(half4*)(outp + OPS + oc) = pm4;
    }
}

// ---------------------------------------------------------------------------
extern "C" void kernel_launch(void* const* d_in, const int* in_sizes, int n_in,
                              void* d_out, int out_size, void* d_ws, size_t ws_size,
                              hipStream_t stream) {
    const int*   idx = (const int*)  d_in[0];
    const float* tok = (const float*)d_in[1];
    const float* pos = (const float*)d_in[2];
    const float* Wq  = (const float*)d_in[3];
    const float* bq  = (const float*)d_in[4];
    const float* Wk  = (const float*)d_in[5];
    const float* bk  = (const float*)d_in[6];
    const float* Wv  = (const float*)d_in[7];
    const float* bv  = (const float*)d_in[8];
    const float* Wo  = (const float*)d_in[9];
    const float* bo  = (const float*)d_in[10];
    const float* W1  = (const float*)d_in[11];
    const float* b1  = (const float*)d_in[12];
    const float* W2  = (const float*)d_in[13];
    const float* b2  = (const float*)d_in[14];
    const float* nw  = (const float*)d_in[15];
    const float* fnw = (const float*)d_in[16];
    const float* Wf  = (const float*)d_in[17];
    const float* bf  = (const float*)d_in[18];
    float* out = (float*)d_out;

    const size_t SZ   = (size_t)BT * DMODEL;
    const size_t HSZF = (size_t)BT * DFF;
    const size_t QPS  = (size_t)BT * QLD;
    const size_t VPS  = (size_t)BATCH * NHEAD * HSZ * T_SEQ;

    char* w = (char*)d_ws;
    auto alloc = [&](size_t bytes) {
        char* p = w;
        w += (bytes + 255) & ~(size_t)255;
        return p;
    };
    float* x    = (float*)alloc(SZ * 4);
    float* xo   = (float*)alloc(SZ * 4);
    f16*   xnp  = (f16*)  alloc(SZ * 2 * 2);
    f16*   qkvp = (f16*)  alloc(QPS * 2 * 2);
    f16*   vTb  = (f16*)  alloc(VPS * 2 * 2);
    f16*   aop  = (f16*)  alloc(SZ * 2 * 2);
    f16*   hbp  = (f16*)  alloc(HSZF * 2 * 2);
    char*  wreg = alloc(132ull * 1024 * 1024);
    f16*   qkvTp = (f16*)wreg;
    f16*   woTp  = qkvTp + 2ull * QLD * DMODEL;
    f16*   w1Tp  = woTp  + 2ull * DMODEL * DMODEL;
    f16*   w2Tp  = w1Tp  + 2ull * DFF * DMODEL;
    f16*   wfp   = (f16*)wreg;
    float* catb  = (float*)alloc((size_t)NLAYER * QLD * 4);

    cat_bias<<<(NLAYER * QLD) / 256, 256, 0, stream>>>(bq, bk, bv, catb);
    embed_kernel<<<BT, 256, 0, stream>>>(idx, tok, pos, x);

    for (int l = 0; l < NLAYER; ++l) {
        const float* nwl = nw + (size_t)l * DMODEL;
        const float* catbl = catb + (size_t)l * QLD;
        const float* bol = bo + (size_t)l * DMODEL;
        const float* b1l = b1 + (size_t)l * DFF;
        const float* b2l = b2 + (size_t)l * DMODEL;

        {
            long izs = (long)DMODEL * HSZ;
            long ozi = (long)HSZ * DMODEL;
            size_t ps = (size_t)QLD * DMODEL;
            dim3 gq(HSZ / 32, DMODEL / 32, NHEAD);
            const float* Wql = Wq + (size_t)l * NHEAD * DMODEL * HSZ;
            const float* Wkl = Wk + (size_t)l * NHEAD * DMODEL * HSZ;
            const float* Wvl = Wv + (size_t)l * NHEAD * DMODEL * HSZ;
            transpose_split<<<gq, 256, 0, stream>>>(Wql, qkvTp,                 ps, DMODEL, HSZ, izs, ozi);
            transpose_split<<<gq, 256, 0, stream>>>(Wkl, qkvTp + 1024ul * 1024, ps, DMODEL, HSZ, izs, ozi);
            transpose_split<<<gq, 256, 0, stream>>>(Wvl, qkvTp + 2048ul * 1024, ps, DMODEL, HSZ, izs, ozi);
            transpose_split<<<dim3(DMODEL / 32, DMODEL / 32, 1), 256, 0, stream>>>(
                Wo + (size_t)l * DMODEL * DMODEL, woTp, (size_t)DMODEL * DMODEL, DMODEL, DMODEL, 0, 0);
            transpose_split<<<dim3(DFF / 32, DMODEL / 32, 1), 256, 0, stream>>>(
                W1 + (size_t)l * DMODEL * DFF, w1Tp, (size_t)DFF * DMODEL, DMODEL, DFF, 0, 0);
            transpose_split<<<dim3(DMODEL / 32, DFF / 32, 1), 256, 0, stream>>>(
                W2 + (size_t)l * DMODEL * DFF, w2Tp, (size_t)DMODEL * DFF, DFF, DMODEL, 0, 0);
        }

        auto attn = [&](const float* resid, float* outp, int causal) {
            gemm_f16<false, true, true><<<dim3((BT / 128) * (QLD / 128)), 512, 0, stream>>>(
                xnp, SZ, qkvTp, (size_t)QLD * DMODEL, catbl, nullptr,
                nullptr, qkvp, QPS, vTb, VPS, QLD, DMODEL);
            if (causal)
                attn_mfma<1><<<dim3(T_SEQ / 64, BATCH * NHEAD), 256, 0, stream>>>(
                    qkvp, QPS, vTb, VPS, aop, SZ);
            else
                attn_mfma<0><<<dim3(T_SEQ / 64, BATCH * NHEAD), 256, 0, stream>>>(
                    qkvp, QPS, vTb, VPS, aop, SZ);
            gemm_f16<false, false, false><<<dim3((BT / 128) * (DMODEL / 128)), 512, 0, stream>>>(
                aop, SZ, woTp, (size_t)DMODEL * DMODEL, bol, resid,
                outp, nullptr, 0, nullptr, 0, DMODEL, DMODEL);
        };

        // x_out1 = x + attn(rms(x), unmasked)
        rms_split<<<BT, 256, 0, stream>>>(x, nwl, xnp, SZ);
        attn(x, xo, 0);
        // x_out2 = x + ffn(rms(x_out1))      (residual from ORIGINAL x)
        rms_split<<<BT, 256, 0, stream>>>(xo, nwl, xnp, SZ);
        gemm_f16<true, true, false><<<dim3((BT / 128) * (DFF / 128)), 512, 0, stream>>>(
            xnp, SZ, w1Tp, (size_t)DFF * DMODEL, b1l, nullptr,
            nullptr, hbp, HSZF, nullptr, 0, DFF, DMODEL);
        gemm_f16<false, false, false><<<dim3((BT / 128) * (DMODEL / 128)), 512, 0, stream>>>(
            hbp, HSZF, w2Tp, (size_t)DMODEL * DFF, b2l, x,
            xo, nullptr, 0, nullptr, 0, DMODEL, DFF);
        // x = x_out2 + attn(rms(x_out2), masked)
        rms_split<<<BT, 256, 0, stream>>>(xo, nwl, xnp, SZ);
        attn(xo, x, 1);
    }

    // final: logits = rms(x, fnw) @ Wf + bf   (single-pass f16, NT stores)
    rms_split<<<BT, 256, 0, stream>>>(x, fnw, xnp, SZ);
    transpose_split<<<dim3(VOCAB / 32, DMODEL / 32, 1), 256, 0, stream>>>(
        Wf, wfp, (size_t)VOCAB * DMODEL, DMODEL, VOCAB, 0, 0);
    gemm_f16_1p<<<dim3((BT / 128) * (VOCAB / 128)), 512, 0, stream>>>(
        xnp, wfp, bf, out, VOCAB, DMODEL);
}

// Round 17
// 5979.843 us; speedup vs baseline: 1.0628x; 1.0628x over previous
//
#include <hip/hip_runtime.h>
#include <hip/hip_bf16.h>
#include <cstdint>
#include <cstddef>

#define T_SEQ   512
#define BATCH   8
#define BT      4096
#define DMODEL  1024
#define NHEAD   16
#define HSZ     64
#define NLAYER  8
#define DFF     4096
#define VOCAB   32000
#define EPS     1e-6f
#define NEG_SLOPE 0.1f
#define QLD     3072
#define MSCALE  2048.0f
#define MINV    (1.0f / 2048.0f)

typedef _Float16 f16;
typedef __attribute__((ext_vector_type(8))) _Float16 half8;
typedef __attribute__((ext_vector_type(4))) _Float16 half4;
typedef __attribute__((ext_vector_type(4))) float f32x4;

#define AS1 __attribute__((address_space(1)))
#define AS3 __attribute__((address_space(3)))

#define WAIT_BAR(N) asm volatile("s_waitcnt vmcnt(" #N ")\ns_barrier" ::: "memory")
#define LGKM_BAR()  asm volatile("s_waitcnt lgkmcnt(0)\ns_barrier" ::: "memory")

// ---------------------------------------------------------------------------
__global__ void embed_kernel(const int* __restrict__ idx,
                             const float* __restrict__ tok,
                             const float* __restrict__ pos,
                             float* __restrict__ x) {
    int bt  = blockIdx.x;
    int tid = threadIdx.x;
    int token = idx[bt];
    int t = bt & (T_SEQ - 1);
    float4 a = reinterpret_cast<const float4*>(tok + (size_t)token * DMODEL)[tid];
    float4 p = reinterpret_cast<const float4*>(pos + (size_t)t * DMODEL)[tid];
    reinterpret_cast<float4*>(x + (size_t)bt * DMODEL)[tid] =
        make_float4(a.x + p.x, a.y + p.y, a.z + p.z, a.w + p.w);
}

// ---------------------------------------------------------------------------
__device__ __forceinline__ void split2h(float v, f16& h, f16& m) {
    f16 hh = (f16)v;
    float hf = (float)hh;
    if (fabsf(hf) < 6.103515625e-05f) { hh = (f16)0.0f; hf = 0.0f; }
    h = hh;
    m = (f16)((v - hf) * MSCALE);
}

// ---------------------------------------------------------------------------
__global__ void rms_split(const float* __restrict__ x,
                          const float* __restrict__ w,
                          f16* __restrict__ out, size_t planeStride) {
    int row = blockIdx.x;
    int tid = threadIdx.x;
    float4 v = reinterpret_cast<const float4*>(x + (size_t)row * DMODEL)[tid];
    float ss = v.x * v.x + v.y * v.y + v.z * v.z + v.w * v.w;
#pragma unroll
    for (int off = 32; off > 0; off >>= 1) ss += __shfl_xor(ss, off);
    __shared__ float wsum[4];
    if ((tid & 63) == 0) wsum[tid >> 6] = ss;
    __syncthreads();
    float tot = wsum[0] + wsum[1] + wsum[2] + wsum[3];
    float scale = rsqrtf(tot * (1.0f / DMODEL) + EPS);
    float4 wv = reinterpret_cast<const float4*>(w)[tid];
    float o[4] = {v.x * scale * wv.x, v.y * scale * wv.y,
                  v.z * scale * wv.z, v.w * scale * wv.w};
    size_t base = (size_t)row * DMODEL + tid * 4;
#pragma unroll
    for (int j = 0; j < 4; ++j) {
        f16 h, m;
        split2h(o[j], h, m);
        out[base + j] = h;
        out[planeStride + base + j] = m;
    }
}

// ---------------------------------------------------------------------------
__global__ __launch_bounds__(256)
void transpose_split(const float* __restrict__ in, f16* __restrict__ out,
                     size_t planeStride, int R, int C,
                     long izs, long ozi) {
    int z = blockIdx.z;
    in  += (size_t)z * izs;
    out += (size_t)z * ozi;
    __shared__ float tile[32][33];
    int r0 = blockIdx.y << 5, c0 = blockIdx.x << 5;
    int tx = threadIdx.x & 31, ty = threadIdx.x >> 5;
#pragma unroll
    for (int i = 0; i < 4; ++i) {
        int r = ty + (i << 3);
        tile[r][tx] = in[(size_t)(r0 + r) * C + c0 + tx];
    }
    __syncthreads();
#pragma unroll
    for (int i = 0; i < 4; ++i) {
        int c = ty + (i << 3);
        float v = tile[tx][c];
        size_t o = (size_t)(c0 + c) * R + r0 + tx;
        f16 h, m;
        split2h(v, h, m);
        out[o] = h;
        out[planeStride + o] = m;
    }
}

// concat per-layer qkv bias into (L, 3072) f32
__global__ void cat_bias(const float* __restrict__ bq, const float* __restrict__ bk,
                         const float* __restrict__ bv, float* __restrict__ cb) {
    int i = blockIdx.x * 256 + threadIdx.x;
    int l = i / QLD, r = i - l * QLD;
    const float* src = (r < 1024) ? bq : ((r < 2048) ? bk : bv);
    cb[i] = src[l * 1024 + (r & 1023)];
}

// ---------------------------------------------------------------------------
// f16 split-GEMM: 3 passes, 2 accumulators, B-single-buffer, 3 barriers/step
// (r15's best-measured schedule, canary-validated).
// VOUT: QKV blocks with n0 >= 2048 write transposed V planes directly.
template <bool LRELU, bool SPLITOUT, bool VOUT>
__global__ __launch_bounds__(512, 4)
void gemm_f16(const f16* __restrict__ A, size_t aPS,
              const f16* __restrict__ Bt, size_t bPS,
              const float* __restrict__ bias,
              const float* __restrict__ resid,
              float* __restrict__ C, f16* __restrict__ Cp, size_t cPS,
              f16* __restrict__ vTp, size_t vPS,
              int N, int K) {
    __shared__ f16 As[2][2 * 4096];
    __shared__ f16 Bs[2 * 4096];

    int chunk = gridDim.x >> 3;
    int bid = blockIdx.x;
    int sw = (bid & 7) * chunk + (bid >> 3);
    int m0 = (sw & 31) << 7;
    int n0 = (sw >> 5) << 7;

    const int tid  = threadIdx.x;
    const int lane = tid & 63;
    const int wid  = tid >> 6;

    const int ssk = (((tid & 3) ^ ((tid >> 3) & 3)) << 3);
    const size_t offA = (size_t)(m0 + (tid >> 2)) * K + ssk;
    const size_t offB = (size_t)(n0 + (tid >> 2)) * K + ssk;
    const int ldst = wid * 512;

    f32x4 accH[4][2], accM[4][2];
#pragma unroll
    for (int i = 0; i < 4; ++i)
#pragma unroll
        for (int j = 0; j < 2; ++j) {
            accH[i][j] = (f32x4){0.f, 0.f, 0.f, 0.f};
            accM[i][j] = (f32x4){0.f, 0.f, 0.f, 0.f};
        }

    const int wr = wid >> 2, wc = wid & 3;
    const int fm = lane & 15;
    const int rslot = (((lane >> 4) ^ ((lane >> 1) & 3)) & 3) << 3;
    const int foffA0 = (wr * 64 + fm) * 32 + rslot;
    const int foffB0 = (wc * 32 + fm) * 32 + rslot;

    auto STAGE_A = [&](int buf, int k0) {
#pragma unroll
        for (int pp = 0; pp < 2; ++pp)
            __builtin_amdgcn_global_load_lds(
                (const AS1 void*)(A + pp * aPS + offA + k0),
                (AS3 void*)(&As[buf][pp * 4096 + ldst]), 16, 0, 0);
    };
    auto STAGE_B = [&](int k0) {
#pragma unroll
        for (int pp = 0; pp < 2; ++pp)
            __builtin_amdgcn_global_load_lds(
                (const AS1 void*)(Bt + pp * bPS + offB + k0),
                (AS3 void*)(&Bs[pp * 4096 + ldst]), 16, 0, 0);
    };

    const int nt = K >> 5;
    STAGE_A(0, 0);
    STAGE_B(0);
    int cur = 0;
    for (int t = 0; t < nt; ++t) {
        if (t + 1 < nt) {
            STAGE_A(cur ^ 1, (t + 1) << 5);
            WAIT_BAR(2);
        } else {
            WAIT_BAR(0);
        }

        half8 bh[2], bm[2];
#pragma unroll
        for (int j = 0; j < 2; ++j) {
            bh[j] = *(const half8*)(&Bs[foffB0 + j * 512]);
            bm[j] = *(const half8*)(&Bs[4096 + foffB0 + j * 512]);
        }
        LGKM_BAR();
        if (t + 1 < nt) STAGE_B((t + 1) << 5);

#pragma unroll
        for (int i = 0; i < 4; ++i) {
            half8 ah = *(const half8*)(&As[cur][foffA0 + i * 512]);
            half8 am = *(const half8*)(&As[cur][4096 + foffA0 + i * 512]);
#pragma unroll
            for (int j = 0; j < 2; ++j) {
                accM[i][j] = __builtin_amdgcn_mfma_f32_16x16x32_f16(
                    am, bh[j], accM[i][j], 0, 0, 0);
                accM[i][j] = __builtin_amdgcn_mfma_f32_16x16x32_f16(
                    ah, bm[j], accM[i][j], 0, 0, 0);
                accH[i][j] = __builtin_amdgcn_mfma_f32_16x16x32_f16(
                    ah, bh[j], accH[i][j], 0, 0, 0);
            }
        }
        LGKM_BAR();
        cur ^= 1;
    }

    const bool vblock = VOUT && (n0 >= 2048);
#pragma unroll
    for (int i = 0; i < 4; ++i) {
        int mbase = m0 + wr * 64 + i * 16 + ((lane >> 4) << 2);
#pragma unroll
        for (int j = 0; j < 2; ++j) {
            int n = n0 + wc * 32 + j * 16 + fm;
            float bv = bias[n];
            if (vblock) {
                half4 ph4, pm4;
#pragma unroll
                for (int rr = 0; rr < 4; ++rr) {
                    float v = accH[i][j][rr] + accM[i][j][rr] * MINV + bv;
                    f16 hh, mm;
                    split2h(v, hh, mm);
                    ph4[rr] = hh;
                    pm4[rr] = mm;
                }
                int nn = n - 2048;
                int bb = mbase >> 9, tt = mbase & 511;
                size_t vo = (((size_t)(bb * 16 + (nn >> 6)) * 64 + (nn & 63)) << 9) + tt;
                *(half4*)(vTp + vo) = ph4;
                *(half4*)(vTp + vPS + vo) = pm4;
            } else {
#pragma unroll
                for (int rr = 0; rr < 4; ++rr) {
                    int m = mbase + rr;
                    float v = accH[i][j][rr] + accM[i][j][rr] * MINV + bv;
                    if (LRELU) v = (v >= 0.f) ? v : NEG_SLOPE * v;
                    size_t o = (size_t)m * N + n;
                    if (SPLITOUT) {
                        f16 h, mm;
                        split2h(v, h, mm);
                        Cp[o] = h;
                        Cp[cPS + o] = mm;
                    } else {
                        if (resid) v += resid[o];
                        C[o] = v;
                    }
                }
            }
        }
    }
}

// ---------------------------------------------------------------------------
// Single-pass plain-f16 vocab GEMM: full dbuf both operands (r16's faster
// variant), 2 barriers/step, NT stores for the write-once C stream.
__global__ __launch_bounds__(512, 4)
void gemm_f16_1p(const f16* __restrict__ A,
                 const f16* __restrict__ Bt,
                 const float* __restrict__ bias,
                 float* __restrict__ C, int N, int K) {
    __shared__ f16 As[2][4096];
    __shared__ f16 Bs[2][4096];

    int chunk = gridDim.x >> 3;
    int bid = blockIdx.x;
    int sw = (bid & 7) * chunk + (bid >> 3);
    int m0 = (sw & 31) << 7;
    int n0 = (sw >> 5) << 7;

    const int tid  = threadIdx.x;
    const int lane = tid & 63;
    const int wid  = tid >> 6;

    const int ssk = (((tid & 3) ^ ((tid >> 3) & 3)) << 3);
    const size_t offA = (size_t)(m0 + (tid >> 2)) * K + ssk;
    const size_t offB = (size_t)(n0 + (tid >> 2)) * K + ssk;
    const int ldst = wid * 512;

    f32x4 acc[4][2];
#pragma unroll
    for (int i = 0; i < 4; ++i)
#pragma unroll
        for (int j = 0; j < 2; ++j) acc[i][j] = (f32x4){0.f, 0.f, 0.f, 0.f};

    const int wr = wid >> 2, wc = wid & 3;
    const int fm = lane & 15;
    const int rslot = (((lane >> 4) ^ ((lane >> 1) & 3)) & 3) << 3;
    const int foffA0 = (wr * 64 + fm) * 32 + rslot;
    const int foffB0 = (wc * 32 + fm) * 32 + rslot;

    auto STAGE = [&](int buf, int k0) {
        __builtin_amdgcn_global_load_lds((const AS1 void*)(A + offA + k0),
                                         (AS3 void*)(&As[buf][ldst]), 16, 0, 0);
        __builtin_amdgcn_global_load_lds((const AS1 void*)(Bt + offB + k0),
                                         (AS3 void*)(&Bs[buf][ldst]), 16, 0, 0);
    };

    const int nt = K >> 5;
    STAGE(0, 0);
    int cur = 0;
    for (int t = 0; t < nt; ++t) {
        if (t + 1 < nt) {
            STAGE(cur ^ 1, (t + 1) << 5);
            WAIT_BAR(2);
        } else {
            WAIT_BAR(0);
        }

        half8 bh[2];
#pragma unroll
        for (int j = 0; j < 2; ++j)
            bh[j] = *(const half8*)(&Bs[cur][foffB0 + j * 512]);
#pragma unroll
        for (int i = 0; i < 4; ++i) {
            half8 ah = *(const half8*)(&As[cur][foffA0 + i * 512]);
#pragma unroll
            for (int j = 0; j < 2; ++j)
                acc[i][j] = __builtin_amdgcn_mfma_f32_16x16x32_f16(
                    ah, bh[j], acc[i][j], 0, 0, 0);
        }
        LGKM_BAR();
        cur ^= 1;
    }

#pragma unroll
    for (int i = 0; i < 4; ++i) {
        int mbase = m0 + wr * 64 + i * 16 + ((lane >> 4) << 2);
#pragma unroll
        for (int j = 0; j < 2; ++j) {
            int n = n0 + wc * 32 + j * 16 + fm;
            float bv = bias[n];
#pragma unroll
            for (int rr = 0; rr < 4; ++rr) {
                int m = mbase + rr;
                __builtin_nontemporal_store(acc[i][j][rr] + bv,
                                            C + (size_t)m * N + n);
            }
        }
    }
}

// ---------------------------------------------------------------------------
// MFMA flash attention, split-f16 3-pass (r14 math, canary-validated).
// r17: 1D grid of 1024 with XCD-affinity swizzle -- each XCD owns 16 complete
// (b,h) heads (K/V working set 4MB = one XCD L2) instead of spreading each
// head's 8 q-tiles across all XCDs. Pure index remap; per-block math identical.
template <int CAUSAL>
__global__ __launch_bounds__(256)
void attn_mfma(const f16* __restrict__ qkvp, size_t QPS,
               const f16* __restrict__ vT, size_t VPS,
               f16* __restrict__ outp, size_t OPS) {
    __shared__ f16 lds[24576];
    const int tid  = threadIdx.x;
    const int lane = tid & 63;
    const int wid  = tid >> 6;
    const int tl   = lane & 15;
    const int g    = lane >> 4;

    // XCD-affinity remap: sw = (bid&7)*128 + bid>>3 ; bh = sw>>3, tile = sw&7
    int bid = blockIdx.x;
    int sw = ((bid & 7) << 7) + (bid >> 3);
    int bh = sw >> 3;
    int qt = sw & 7;
    int b = bh >> 4, h = bh & 15;
    int t0 = qt << 6;
    const int PB = 16384 + wid * 2048;

    half8 Qh[2], Qm[2];
    {
        const f16* qb = qkvp + (size_t)(b * 512 + t0 + wid * 16 + tl) * 3072
                        + h * 64 + (g << 3);
        Qh[0] = *(const half8*)(qb);
        Qh[1] = *(const half8*)(qb + 32);
        Qm[0] = *(const half8*)(qb + QPS);
        Qm[1] = *(const half8*)(qb + QPS + 32);
    }

    f32x4 oH[4], oM[4];
#pragma unroll
    for (int en = 0; en < 4; ++en) {
        oH[en] = (f32x4){0.f, 0.f, 0.f, 0.f};
        oM[en] = (f32x4){0.f, 0.f, 0.f, 0.f};
    }
    float m_run = -INFINITY, l_run = 0.f;

    auto STAGE1 = [&](int ldsOff, const f16* srcBase, int rowStride) {
#pragma unroll
        for (int it = 0; it < 2; ++it) {
            int r  = (tid >> 3) + it * 32;
            int cp = (tid & 7) ^ (r & 7);
            __builtin_amdgcn_global_load_lds(
                (const AS1 void*)(srcBase + (size_t)r * rowStride + cp * 8),
                (AS3 void*)(lds + ldsOff + (it * 32 + wid * 8) * 64), 16, 0, 0);
        }
    };

    const int NT = CAUSAL ? (qt + 1) : (T_SEQ / 64);
    for (int st = 0; st < NT; ++st) {
        int s0 = st << 6;
        {
            const f16* kS = qkvp + (size_t)(b * 512 + s0) * 3072 + 1024 + h * 64;
            const f16* vS = vT + ((size_t)(bh * 64) << 9) + s0;
            STAGE1(0,     kS, 3072);
            STAGE1(4096,  kS + QPS, 3072);
            STAGE1(8192,  vS, 512);
            STAGE1(12288, vS + VPS, 512);
        }
        __syncthreads();

        f32x4 sH[4], sM[4];
#pragma unroll
        for (int sm = 0; sm < 4; ++sm) {
            sH[sm] = (f32x4){0.f, 0.f, 0.f, 0.f};
            sM[sm] = (f32x4){0.f, 0.f, 0.f, 0.f};
        }
#pragma unroll
        for (int sm = 0; sm < 4; ++sm) {
            int sl = sm * 16 + tl;
#pragma unroll
            for (int kf = 0; kf < 2; ++kf) {
                int sp = ((kf * 4 + g) ^ (sl & 7)) << 3;
                half8 kh = *(const half8*)(lds + sl * 64 + sp);
                half8 km = *(const half8*)(lds + 4096 + sl * 64 + sp);
                sM[sm] = __builtin_amdgcn_mfma_f32_16x16x32_f16(km, Qh[kf], sM[sm], 0, 0, 0);
                sM[sm] = __builtin_amdgcn_mfma_f32_16x16x32_f16(kh, Qm[kf], sM[sm], 0, 0, 0);
                sH[sm] = __builtin_amdgcn_mfma_f32_16x16x32_f16(kh, Qh[kf], sH[sm], 0, 0, 0);
            }
        }

        float sv[4][4];
#pragma unroll
        for (int sm = 0; sm < 4; ++sm)
#pragma unroll
            for (int rr = 0; rr < 4; ++rr) {
                float v = (sH[sm][rr] + sM[sm][rr] * MINV) * 8.0f;
                if (CAUSAL && st == NT - 1) {
                    int sg = s0 + sm * 16 + (g << 2) + rr;
                    int tg = t0 + wid * 16 + tl;
                    if (sg > tg) v = -INFINITY;
                }
                sv[sm][rr] = v;
            }
        float rmax = -INFINITY;
#pragma unroll
        for (int sm = 0; sm < 4; ++sm)
#pragma unroll
            for (int rr = 0; rr < 4; ++rr) rmax = fmaxf(rmax, sv[sm][rr]);
        rmax = fmaxf(rmax, __shfl_xor(rmax, 16));
        rmax = fmaxf(rmax, __shfl_xor(rmax, 32));
        float mn = fmaxf(m_run, rmax);
        float fsc = __expf(m_run - mn);
        float rs = 0.f;
#pragma unroll
        for (int sm = 0; sm < 4; ++sm)
#pragma unroll
            for (int rr = 0; rr < 4; ++rr) {
                float p = __expf(sv[sm][rr] - mn);
                sv[sm][rr] = p;
                rs += p;
            }
        rs += __shfl_xor(rs, 16);
        rs += __shfl_xor(rs, 32);
        l_run = l_run * fsc + rs;
        m_run = mn;
#pragma unroll
        for (int en = 0; en < 4; ++en)
#pragma unroll
            for (int rr = 0; rr < 4; ++rr) {
                oH[en][rr] *= fsc;
                oM[en][rr] *= fsc;
            }

#pragma unroll
        for (int sm = 0; sm < 4; ++sm) {
            half4 ph4, pm4;
#pragma unroll
            for (int rr = 0; rr < 4; ++rr) {
                f16 hh, mm;
                split2h(sv[sm][rr], hh, mm);
                ph4[rr] = hh;
                pm4[rr] = mm;
            }
            int sbase = sm * 16 + (g << 2);
            int sp = (sbase >> 3) ^ (tl & 7);
            int eo = PB + tl * 64 + sp * 8 + (sbase & 7);
            *(half4*)(lds + eo) = ph4;
            *(half4*)(lds + eo + 1024) = pm4;
        }
        asm volatile("s_waitcnt lgkmcnt(0)" ::: "memory");
        __builtin_amdgcn_sched_barrier(0);

        half8 Ph[2], Pm[2];
#pragma unroll
        for (int kf = 0; kf < 2; ++kf) {
            int sp = ((kf * 4 + g) ^ (tl & 7)) << 3;
            Ph[kf] = *(const half8*)(lds + PB + tl * 64 + sp);
            Pm[kf] = *(const half8*)(lds + PB + 1024 + tl * 64 + sp);
        }
#pragma unroll
        for (int en = 0; en < 4; ++en) {
            int el = en * 16 + tl;
#pragma unroll
            for (int kf = 0; kf < 2; ++kf) {
                int sp = ((kf * 4 + g) ^ (el & 7)) << 3;
                half8 vh = *(const half8*)(lds + 8192 + el * 64 + sp);
                half8 vm = *(const half8*)(lds + 12288 + el * 64 + sp);
                oM[en] = __builtin_amdgcn_mfma_f32_16x16x32_f16(vm, Ph[kf], oM[en], 0, 0, 0);
                oM[en] = __builtin_amdgcn_mfma_f32_16x16x32_f16(vh, Pm[kf], oM[en], 0, 0, 0);
                oH[en] = __builtin_amdgcn_mfma_f32_16x16x32_f16(vh, Ph[kf], oH[en], 0, 0, 0);
            }
        }
        __syncthreads();
    }

    float inv = 1.f / l_run;
    size_t obase = (size_t)(b * 512 + t0 + wid * 16 + tl) * 1024 + h * 64;
#pragma unroll
    for (int en = 0; en < 4; ++en) {
        half4 ph4, pm4;
#pragma unroll
        for (int rr = 0; rr < 4; ++rr) {
            float v = (oH[en][rr] + oM[en][rr] * MINV) * inv;
            f16 hh, mm;
            split2h(v, hh, mm);
            ph4[rr] = hh;
            pm4[rr] = mm;
        }
        size_t oc = obase + en * 16 + (g << 2);
        *(half4*)(outp + oc) = ph4;
        *(half4*)(outp + OPS + oc) = pm4;
    }
}

// ---------------------------------------------------------------------------
extern "C" void kernel_launch(void* const* d_in, const int* in_sizes, int n_in,
                              void* d_out, int out_size, void* d_ws, size_t ws_size,
                              hipStream_t stream) {
    const int*   idx = (const int*)  d_in[0];
    const float* tok = (const float*)d_in[1];
    const float* pos = (const float*)d_in[2];
    const float* Wq  = (const float*)d_in[3];
    const float* bq  = (const float*)d_in[4];
    const float* Wk  = (const float*)d_in[5];
    const float* bk  = (const float*)d_in[6];
    const float* Wv  = (const float*)d_in[7];
    const float* bv  = (const float*)d_in[8];
    const float* Wo  = (const float*)d_in[9];
    const float* bo  = (const float*)d_in[10];
    const float* W1  = (const float*)d_in[11];
    const float* b1  = (const float*)d_in[12];
    const float* W2  = (const float*)d_in[13];
    const float* b2  = (const float*)d_in[14];
    const float* nw  = (const float*)d_in[15];
    const float* fnw = (const float*)d_in[16];
    const float* Wf  = (const float*)d_in[17];
    const float* bf  = (const float*)d_in[18];
    float* out = (float*)d_out;

    const size_t SZ   = (size_t)BT * DMODEL;
    const size_t HSZF = (size_t)BT * DFF;
    const size_t QPS  = (size_t)BT * QLD;
    const size_t VPS  = (size_t)BATCH * NHEAD * HSZ * T_SEQ;

    char* w = (char*)d_ws;
    auto alloc = [&](size_t bytes) {
        char* p = w;
        w += (bytes + 255) & ~(size_t)255;
        return p;
    };
    float* x    = (float*)alloc(SZ * 4);
    float* xo   = (float*)alloc(SZ * 4);
    f16*   xnp  = (f16*)  alloc(SZ * 2 * 2);
    f16*   qkvp = (f16*)  alloc(QPS * 2 * 2);
    f16*   vTb  = (f16*)  alloc(VPS * 2 * 2);
    f16*   aop  = (f16*)  alloc(SZ * 2 * 2);
    f16*   hbp  = (f16*)  alloc(HSZF * 2 * 2);
    char*  wreg = alloc(132ull * 1024 * 1024);
    f16*   qkvTp = (f16*)wreg;
    f16*   woTp  = qkvTp + 2ull * QLD * DMODEL;
    f16*   w1Tp  = woTp  + 2ull * DMODEL * DMODEL;
    f16*   w2Tp  = w1Tp  + 2ull * DFF * DMODEL;
    f16*   wfp   = (f16*)wreg;
    float* catb  = (float*)alloc((size_t)NLAYER * QLD * 4);

    cat_bias<<<(NLAYER * QLD) / 256, 256, 0, stream>>>(bq, bk, bv, catb);
    embed_kernel<<<BT, 256, 0, stream>>>(idx, tok, pos, x);

    for (int l = 0; l < NLAYER; ++l) {
        const float* nwl = nw + (size_t)l * DMODEL;
        const float* catbl = catb + (size_t)l * QLD;
        const float* bol = bo + (size_t)l * DMODEL;
        const float* b1l = b1 + (size_t)l * DFF;
        const float* b2l = b2 + (size_t)l * DMODEL;

        {
            long izs = (long)DMODEL * HSZ;
            long ozi = (long)HSZ * DMODEL;
            size_t ps = (size_t)QLD * DMODEL;
            dim3 gq(HSZ / 32, DMODEL / 32, NHEAD);
            const float* Wql = Wq + (size_t)l * NHEAD * DMODEL * HSZ;
            const float* Wkl = Wk + (size_t)l * NHEAD * DMODEL * HSZ;
            const float* Wvl = Wv + (size_t)l * NHEAD * DMODEL * HSZ;
            transpose_split<<<gq, 256, 0, stream>>>(Wql, qkvTp,                 ps, DMODEL, HSZ, izs, ozi);
            transpose_split<<<gq, 256, 0, stream>>>(Wkl, qkvTp + 1024ul * 1024, ps, DMODEL, HSZ, izs, ozi);
            transpose_split<<<gq, 256, 0, stream>>>(Wvl, qkvTp + 2048ul * 1024, ps, DMODEL, HSZ, izs, ozi);
            transpose_split<<<dim3(DMODEL / 32, DMODEL / 32, 1), 256, 0, stream>>>(
                Wo + (size_t)l * DMODEL * DMODEL, woTp, (size_t)DMODEL * DMODEL, DMODEL, DMODEL, 0, 0);
            transpose_split<<<dim3(DFF / 32, DMODEL / 32, 1), 256, 0, stream>>>(
                W1 + (size_t)l * DMODEL * DFF, w1Tp, (size_t)DFF * DMODEL, DMODEL, DFF, 0, 0);
            transpose_split<<<dim3(DMODEL / 32, DFF / 32, 1), 256, 0, stream>>>(
                W2 + (size_t)l * DMODEL * DFF, w2Tp, (size_t)DMODEL * DFF, DFF, DMODEL, 0, 0);
        }

        auto attn = [&](const float* resid, float* outp, int causal) {
            gemm_f16<false, true, true><<<dim3((BT / 128) * (QLD / 128)), 512, 0, stream>>>(
                xnp, SZ, qkvTp, (size_t)QLD * DMODEL, catbl, nullptr,
                nullptr, qkvp, QPS, vTb, VPS, QLD, DMODEL);
            if (causal)
                attn_mfma<1><<<dim3(1024), 256, 0, stream>>>(
                    qkvp, QPS, vTb, VPS, aop, SZ);
            else
                attn_mfma<0><<<dim3(1024), 256, 0, stream>>>(
                    qkvp, QPS, vTb, VPS, aop, SZ);
            gemm_f16<false, false, false><<<dim3((BT / 128) * (DMODEL / 128)), 512, 0, stream>>>(
                aop, SZ, woTp, (size_t)DMODEL * DMODEL, bol, resid,
                outp, nullptr, 0, nullptr, 0, DMODEL, DMODEL);
        };

        // x_out1 = x + attn(rms(x), unmasked)
        rms_split<<<BT, 256, 0, stream>>>(x, nwl, xnp, SZ);
        attn(x, xo, 0);
        // x_out2 = x + ffn(rms(x_out1))      (residual from ORIGINAL x)
        rms_split<<<BT, 256, 0, stream>>>(xo, nwl, xnp, SZ);
        gemm_f16<true, true, false><<<dim3((BT / 128) * (DFF / 128)), 512, 0, stream>>>(
            xnp, SZ, w1Tp, (size_t)DFF * DMODEL, b1l, nullptr,
            nullptr, hbp, HSZF, nullptr, 0, DFF, DMODEL);
        gemm_f16<false, false, false><<<dim3((BT / 128) * (DMODEL / 128)), 512, 0, stream>>>(
            hbp, HSZF, w2Tp, (size_t)DMODEL * DFF, b2l, x,
            xo, nullptr, 0, nullptr, 0, DMODEL, DFF);
        // x = x_out2 + attn(rms(x_out2), masked)
        rms_split<<<BT, 256, 0, stream>>>(xo, nwl, xnp, SZ);
        attn(xo, x, 1);
    }

    // final: logits = rms(x, fnw) @ Wf + bf   (single-pass f16, NT stores)
    rms_split<<<BT, 256, 0, stream>>>(x, fnw, xnp, SZ);
    transpose_split<<<dim3(VOCAB / 32, DMODEL / 32, 1), 256, 0, stream>>>(
        Wf, wfp, (size_t)VOCAB * DMODEL, DMODEL, VOCAB, 0, 0);
    gemm_f16_1p<<<dim3((BT / 128) * (VOCAB / 128)), 512, 0, stream>>>(
        xnp, wfp, bf, out, VOCAB, DMODEL);
}

// Round 18
// 5751.065 us; speedup vs baseline: 1.1051x; 1.0398x over previous
//
#include <hip/hip_runtime.h>
#include <hip/hip_bf16.h>
#include <cstdint>
#include <cstddef>

#define T_SEQ   512
#define BATCH   8
#define BT      4096
#define DMODEL  1024
#define NHEAD   16
#define HSZ     64
#define NLAYER  8
#define DFF     4096
#define VOCAB   32000
#define EPS     1e-6f
#define NEG_SLOPE 0.1f
#define QLD     3072
#define MSCALE  2048.0f
#define MINV    (1.0f / 2048.0f)

typedef _Float16 f16;
typedef __attribute__((ext_vector_type(8))) _Float16 half8;
typedef __attribute__((ext_vector_type(4))) _Float16 half4;
typedef __attribute__((ext_vector_type(4))) float f32x4;

#define AS1 __attribute__((address_space(1)))
#define AS3 __attribute__((address_space(3)))

#define WAIT_BAR(N) asm volatile("s_waitcnt vmcnt(" #N ")\ns_barrier" ::: "memory")
#define LGKM_BAR()  asm volatile("s_waitcnt lgkmcnt(0)\ns_barrier" ::: "memory")

// ---------------------------------------------------------------------------
__global__ void embed_kernel(const int* __restrict__ idx,
                             const float* __restrict__ tok,
                             const float* __restrict__ pos,
                             float* __restrict__ x) {
    int bt  = blockIdx.x;
    int tid = threadIdx.x;
    int token = idx[bt];
    int t = bt & (T_SEQ - 1);
    float4 a = reinterpret_cast<const float4*>(tok + (size_t)token * DMODEL)[tid];
    float4 p = reinterpret_cast<const float4*>(pos + (size_t)t * DMODEL)[tid];
    reinterpret_cast<float4*>(x + (size_t)bt * DMODEL)[tid] =
        make_float4(a.x + p.x, a.y + p.y, a.z + p.z, a.w + p.w);
}

// ---------------------------------------------------------------------------
__device__ __forceinline__ void split2h(float v, f16& h, f16& m) {
    f16 hh = (f16)v;
    float hf = (float)hh;
    if (fabsf(hf) < 6.103515625e-05f) { hh = (f16)0.0f; hf = 0.0f; }
    h = hh;
    m = (f16)((v - hf) * MSCALE);
}

// ---------------------------------------------------------------------------
__global__ void rms_split(const float* __restrict__ x,
                          const float* __restrict__ w,
                          f16* __restrict__ out, size_t planeStride) {
    int row = blockIdx.x;
    int tid = threadIdx.x;
    float4 v = reinterpret_cast<const float4*>(x + (size_t)row * DMODEL)[tid];
    float ss = v.x * v.x + v.y * v.y + v.z * v.z + v.w * v.w;
#pragma unroll
    for (int off = 32; off > 0; off >>= 1) ss += __shfl_xor(ss, off);
    __shared__ float wsum[4];
    if ((tid & 63) == 0) wsum[tid >> 6] = ss;
    __syncthreads();
    float tot = wsum[0] + wsum[1] + wsum[2] + wsum[3];
    float scale = rsqrtf(tot * (1.0f / DMODEL) + EPS);
    float4 wv = reinterpret_cast<const float4*>(w)[tid];
    float o[4] = {v.x * scale * wv.x, v.y * scale * wv.y,
                  v.z * scale * wv.z, v.w * scale * wv.w};
    size_t base = (size_t)row * DMODEL + tid * 4;
#pragma unroll
    for (int j = 0; j < 4; ++j) {
        f16 h, m;
        split2h(o[j], h, m);
        out[base + j] = h;
        out[planeStride + base + j] = m;
    }
}

// ---------------------------------------------------------------------------
__global__ __launch_bounds__(256)
void transpose_split(const float* __restrict__ in, f16* __restrict__ out,
                     size_t planeStride, int R, int C,
                     long izs, long ozi) {
    int z = blockIdx.z;
    in  += (size_t)z * izs;
    out += (size_t)z * ozi;
    __shared__ float tile[32][33];
    int r0 = blockIdx.y << 5, c0 = blockIdx.x << 5;
    int tx = threadIdx.x & 31, ty = threadIdx.x >> 5;
#pragma unroll
    for (int i = 0; i < 4; ++i) {
        int r = ty + (i << 3);
        tile[r][tx] = in[(size_t)(r0 + r) * C + c0 + tx];
    }
    __syncthreads();
#pragma unroll
    for (int i = 0; i < 4; ++i) {
        int c = ty + (i << 3);
        float v = tile[tx][c];
        size_t o = (size_t)(c0 + c) * R + r0 + tx;
        f16 h, m;
        split2h(v, h, m);
        out[o] = h;
        out[planeStride + o] = m;
    }
}

// concat per-layer qkv bias into (L, 3072) f32
__global__ void cat_bias(const float* __restrict__ bq, const float* __restrict__ bk,
                         const float* __restrict__ bv, float* __restrict__ cb) {
    int i = blockIdx.x * 256 + threadIdx.x;
    int l = i / QLD, r = i - l * QLD;
    const float* src = (r < 1024) ? bq : ((r < 2048) ? bk : bv);
    cb[i] = src[l * 1024 + (r & 1023)];
}

// ---------------------------------------------------------------------------
// f16 split-GEMM, r18: full dbuf both operands (64KB, 2 blk/CU), 2 barriers
// per step with SPREAD staging: A(t+1) at step-top (WAIT_BAR(2) keeps it in
// flight, drains A(t),B(t)); B(t+1) mid-body after the B-frag reads (targets
// the other buffer; prior-step reads protected by the end LGKM_BAR).
// vmcnt FIFO: top outstanding = A(t):2+B(t):2; issue A(t+1):2; WAIT_BAR(2).
// Per-element accumulation order identical to r13..r17 (absmax canary).
// VOUT: QKV blocks with n0 >= 2048 write transposed V planes directly.
template <bool LRELU, bool SPLITOUT, bool VOUT>
__global__ __launch_bounds__(512, 4)
void gemm_f16(const f16* __restrict__ A, size_t aPS,
              const f16* __restrict__ Bt, size_t bPS,
              const float* __restrict__ bias,
              const float* __restrict__ resid,
              float* __restrict__ C, f16* __restrict__ Cp, size_t cPS,
              f16* __restrict__ vTp, size_t vPS,
              int N, int K) {
    __shared__ f16 As[2][2 * 4096];
    __shared__ f16 Bs[2][2 * 4096];

    int chunk = gridDim.x >> 3;
    int bid = blockIdx.x;
    int sw = (bid & 7) * chunk + (bid >> 3);
    int m0 = (sw & 31) << 7;
    int n0 = (sw >> 5) << 7;

    const int tid  = threadIdx.x;
    const int lane = tid & 63;
    const int wid  = tid >> 6;

    const int ssk = (((tid & 3) ^ ((tid >> 3) & 3)) << 3);
    const size_t offA = (size_t)(m0 + (tid >> 2)) * K + ssk;
    const size_t offB = (size_t)(n0 + (tid >> 2)) * K + ssk;
    const int ldst = wid * 512;

    f32x4 accH[4][2], accM[4][2];
#pragma unroll
    for (int i = 0; i < 4; ++i)
#pragma unroll
        for (int j = 0; j < 2; ++j) {
            accH[i][j] = (f32x4){0.f, 0.f, 0.f, 0.f};
            accM[i][j] = (f32x4){0.f, 0.f, 0.f, 0.f};
        }

    const int wr = wid >> 2, wc = wid & 3;
    const int fm = lane & 15;
    const int rslot = (((lane >> 4) ^ ((lane >> 1) & 3)) & 3) << 3;
    const int foffA0 = (wr * 64 + fm) * 32 + rslot;
    const int foffB0 = (wc * 32 + fm) * 32 + rslot;

    auto STAGE_A = [&](int buf, int k0) {
#pragma unroll
        for (int pp = 0; pp < 2; ++pp)
            __builtin_amdgcn_global_load_lds(
                (const AS1 void*)(A + pp * aPS + offA + k0),
                (AS3 void*)(&As[buf][pp * 4096 + ldst]), 16, 0, 0);
    };
    auto STAGE_B = [&](int buf, int k0) {
#pragma unroll
        for (int pp = 0; pp < 2; ++pp)
            __builtin_amdgcn_global_load_lds(
                (const AS1 void*)(Bt + pp * bPS + offB + k0),
                (AS3 void*)(&Bs[buf][pp * 4096 + ldst]), 16, 0, 0);
    };

    const int nt = K >> 5;
    STAGE_A(0, 0);
    STAGE_B(0, 0);
    int cur = 0;
    for (int t = 0; t < nt; ++t) {
        if (t + 1 < nt) {
            STAGE_A(cur ^ 1, (t + 1) << 5);
            WAIT_BAR(2);
        } else {
            WAIT_BAR(0);
        }

        half8 bh[2], bm[2];
#pragma unroll
        for (int j = 0; j < 2; ++j) {
            bh[j] = *(const half8*)(&Bs[cur][foffB0 + j * 512]);
            bm[j] = *(const half8*)(&Bs[cur][4096 + foffB0 + j * 512]);
        }
        if (t + 1 < nt) STAGE_B(cur ^ 1, (t + 1) << 5);   // other buffer: no
                                                          // barrier needed here

#pragma unroll
        for (int i = 0; i < 4; ++i) {
            half8 ah = *(const half8*)(&As[cur][foffA0 + i * 512]);
            half8 am = *(const half8*)(&As[cur][4096 + foffA0 + i * 512]);
#pragma unroll
            for (int j = 0; j < 2; ++j) {
                accM[i][j] = __builtin_amdgcn_mfma_f32_16x16x32_f16(
                    am, bh[j], accM[i][j], 0, 0, 0);
                accM[i][j] = __builtin_amdgcn_mfma_f32_16x16x32_f16(
                    ah, bm[j], accM[i][j], 0, 0, 0);
                accH[i][j] = __builtin_amdgcn_mfma_f32_16x16x32_f16(
                    ah, bh[j], accH[i][j], 0, 0, 0);
            }
        }
        LGKM_BAR();     // all waves' ds_reads of buf[cur] complete before the
                        // next step's staging overwrites it
        cur ^= 1;
    }

    const bool vblock = VOUT && (n0 >= 2048);
#pragma unroll
    for (int i = 0; i < 4; ++i) {
        int mbase = m0 + wr * 64 + i * 16 + ((lane >> 4) << 2);
#pragma unroll
        for (int j = 0; j < 2; ++j) {
            int n = n0 + wc * 32 + j * 16 + fm;
            float bv = bias[n];
            if (vblock) {
                half4 ph4, pm4;
#pragma unroll
                for (int rr = 0; rr < 4; ++rr) {
                    float v = accH[i][j][rr] + accM[i][j][rr] * MINV + bv;
                    f16 hh, mm;
                    split2h(v, hh, mm);
                    ph4[rr] = hh;
                    pm4[rr] = mm;
                }
                int nn = n - 2048;
                int bb = mbase >> 9, tt = mbase & 511;
                size_t vo = (((size_t)(bb * 16 + (nn >> 6)) * 64 + (nn & 63)) << 9) + tt;
                *(half4*)(vTp + vo) = ph4;
                *(half4*)(vTp + vPS + vo) = pm4;
            } else {
#pragma unroll
                for (int rr = 0; rr < 4; ++rr) {
                    int m = mbase + rr;
                    float v = accH[i][j][rr] + accM[i][j][rr] * MINV + bv;
                    if (LRELU) v = (v >= 0.f) ? v : NEG_SLOPE * v;
                    size_t o = (size_t)m * N + n;
                    if (SPLITOUT) {
                        f16 h, mm;
                        split2h(v, h, mm);
                        Cp[o] = h;
                        Cp[cPS + o] = mm;
                    } else {
                        if (resid) v += resid[o];
                        C[o] = v;
                    }
                }
            }
        }
    }
}

// ---------------------------------------------------------------------------
// Single-pass plain-f16 vocab GEMM (r16/r17's best-measured variant):
// full dbuf both operands, 2 barriers/step, NT stores.
__global__ __launch_bounds__(512, 4)
void gemm_f16_1p(const f16* __restrict__ A,
                 const f16* __restrict__ Bt,
                 const float* __restrict__ bias,
                 float* __restrict__ C, int N, int K) {
    __shared__ f16 As[2][4096];
    __shared__ f16 Bs[2][4096];

    int chunk = gridDim.x >> 3;
    int bid = blockIdx.x;
    int sw = (bid & 7) * chunk + (bid >> 3);
    int m0 = (sw & 31) << 7;
    int n0 = (sw >> 5) << 7;

    const int tid  = threadIdx.x;
    const int lane = tid & 63;
    const int wid  = tid >> 6;

    const int ssk = (((tid & 3) ^ ((tid >> 3) & 3)) << 3);
    const size_t offA = (size_t)(m0 + (tid >> 2)) * K + ssk;
    const size_t offB = (size_t)(n0 + (tid >> 2)) * K + ssk;
    const int ldst = wid * 512;

    f32x4 acc[4][2];
#pragma unroll
    for (int i = 0; i < 4; ++i)
#pragma unroll
        for (int j = 0; j < 2; ++j) acc[i][j] = (f32x4){0.f, 0.f, 0.f, 0.f};

    const int wr = wid >> 2, wc = wid & 3;
    const int fm = lane & 15;
    const int rslot = (((lane >> 4) ^ ((lane >> 1) & 3)) & 3) << 3;
    const int foffA0 = (wr * 64 + fm) * 32 + rslot;
    const int foffB0 = (wc * 32 + fm) * 32 + rslot;

    auto STAGE = [&](int buf, int k0) {
        __builtin_amdgcn_global_load_lds((const AS1 void*)(A + offA + k0),
                                         (AS3 void*)(&As[buf][ldst]), 16, 0, 0);
        __builtin_amdgcn_global_load_lds((const AS1 void*)(Bt + offB + k0),
                                         (AS3 void*)(&Bs[buf][ldst]), 16, 0, 0);
    };

    const int nt = K >> 5;
    STAGE(0, 0);
    int cur = 0;
    for (int t = 0; t < nt; ++t) {
        if (t + 1 < nt) {
            STAGE(cur ^ 1, (t + 1) << 5);
            WAIT_BAR(2);
        } else {
            WAIT_BAR(0);
        }

        half8 bh[2];
#pragma unroll
        for (int j = 0; j < 2; ++j)
            bh[j] = *(const half8*)(&Bs[cur][foffB0 + j * 512]);
#pragma unroll
        for (int i = 0; i < 4; ++i) {
            half8 ah = *(const half8*)(&As[cur][foffA0 + i * 512]);
#pragma unroll
            for (int j = 0; j < 2; ++j)
                acc[i][j] = __builtin_amdgcn_mfma_f32_16x16x32_f16(
                    ah, bh[j], acc[i][j], 0, 0, 0);
        }
        LGKM_BAR();
        cur ^= 1;
    }

#pragma unroll
    for (int i = 0; i < 4; ++i) {
        int mbase = m0 + wr * 64 + i * 16 + ((lane >> 4) << 2);
#pragma unroll
        for (int j = 0; j < 2; ++j) {
            int n = n0 + wc * 32 + j * 16 + fm;
            float bv = bias[n];
#pragma unroll
            for (int rr = 0; rr < 4; ++rr) {
                int m = mbase + rr;
                __builtin_nontemporal_store(acc[i][j][rr] + bv,
                                            C + (size_t)m * N + n);
            }
        }
    }
}

// ---------------------------------------------------------------------------
// MFMA flash attention, split-f16 3-pass, XCD-affinity grid (r17-identical).
template <int CAUSAL>
__global__ __launch_bounds__(256)
void attn_mfma(const f16* __restrict__ qkvp, size_t QPS,
               const f16* __restrict__ vT, size_t VPS,
               f16* __restrict__ outp, size_t OPS) {
    __shared__ f16 lds[24576];
    const int tid  = threadIdx.x;
    const int lane = tid & 63;
    const int wid  = tid >> 6;
    const int tl   = lane & 15;
    const int g    = lane >> 4;

    int bid = blockIdx.x;
    int sw = ((bid & 7) << 7) + (bid >> 3);
    int bh = sw >> 3;
    int qt = sw & 7;
    int b = bh >> 4, h = bh & 15;
    int t0 = qt << 6;
    const int PB = 16384 + wid * 2048;

    half8 Qh[2], Qm[2];
    {
        const f16* qb = qkvp + (size_t)(b * 512 + t0 + wid * 16 + tl) * 3072
                        + h * 64 + (g << 3);
        Qh[0] = *(const half8*)(qb);
        Qh[1] = *(const half8*)(qb + 32);
        Qm[0] = *(const half8*)(qb + QPS);
        Qm[1] = *(const half8*)(qb + QPS + 32);
    }

    f32x4 oH[4], oM[4];
#pragma unroll
    for (int en = 0; en < 4; ++en) {
        oH[en] = (f32x4){0.f, 0.f, 0.f, 0.f};
        oM[en] = (f32x4){0.f, 0.f, 0.f, 0.f};
    }
    float m_run = -INFINITY, l_run = 0.f;

    auto STAGE1 = [&](int ldsOff, const f16* srcBase, int rowStride) {
#pragma unroll
        for (int it = 0; it < 2; ++it) {
            int r  = (tid >> 3) + it * 32;
            int cp = (tid & 7) ^ (r & 7);
            __builtin_amdgcn_global_load_lds(
                (const AS1 void*)(srcBase + (size_t)r * rowStride + cp * 8),
                (AS3 void*)(lds + ldsOff + (it * 32 + wid * 8) * 64), 16, 0, 0);
        }
    };

    const int NT = CAUSAL ? (qt + 1) : (T_SEQ / 64);
    for (int st = 0; st < NT; ++st) {
        int s0 = st << 6;
        {
            const f16* kS = qkvp + (size_t)(b * 512 + s0) * 3072 + 1024 + h * 64;
            const f16* vS = vT + ((size_t)(bh * 64) << 9) + s0;
            STAGE1(0,     kS, 3072);
            STAGE1(4096,  kS + QPS, 3072);
            STAGE1(8192,  vS, 512);
            STAGE1(12288, vS + VPS, 512);
        }
        __syncthreads();

        f32x4 sH[4], sM[4];
#pragma unroll
        for (int sm = 0; sm < 4; ++sm) {
            sH[sm] = (f32x4){0.f, 0.f, 0.f, 0.f};
            sM[sm] = (f32x4){0.f, 0.f, 0.f, 0.f};
        }
#pragma unroll
        for (int sm = 0; sm < 4; ++sm) {
            int sl = sm * 16 + tl;
#pragma unroll
            for (int kf = 0; kf < 2; ++kf) {
                int sp = ((kf * 4 + g) ^ (sl & 7)) << 3;
                half8 kh = *(const half8*)(lds + sl * 64 + sp);
                half8 km = *(const half8*)(lds + 4096 + sl * 64 + sp);
                sM[sm] = __builtin_amdgcn_mfma_f32_16x16x32_f16(km, Qh[kf], sM[sm], 0, 0, 0);
                sM[sm] = __builtin_amdgcn_mfma_f32_16x16x32_f16(kh, Qm[kf], sM[sm], 0, 0, 0);
                sH[sm] = __builtin_amdgcn_mfma_f32_16x16x32_f16(kh, Qh[kf], sH[sm], 0, 0, 0);
            }
        }

        float sv[4][4];
#pragma unroll
        for (int sm = 0; sm < 4; ++sm)
#pragma unroll
            for (int rr = 0; rr < 4; ++rr) {
                float v = (sH[sm][rr] + sM[sm][rr] * MINV) * 8.0f;
                if (CAUSAL && st == NT - 1) {
                    int sg = s0 + sm * 16 + (g << 2) + rr;
                    int tg = t0 + wid * 16 + tl;
                    if (sg > tg) v = -INFINITY;
                }
                sv[sm][rr] = v;
            }
        float rmax = -INFINITY;
#pragma unroll
        for (int sm = 0; sm < 4; ++sm)
#pragma unroll
            for (int rr = 0; rr < 4; ++rr) rmax = fmaxf(rmax, sv[sm][rr]);
        rmax = fmaxf(rmax, __shfl_xor(rmax, 16));
        rmax = fmaxf(rmax, __shfl_xor(rmax, 32));
        float mn = fmaxf(m_run, rmax);
        float fsc = __expf(m_run - mn);
        float rs = 0.f;
#pragma unroll
        for (int sm = 0; sm < 4; ++sm)
#pragma unroll
            for (int rr = 0; rr < 4; ++rr) {
                float p = __expf(sv[sm][rr] - mn);
                sv[sm][rr] = p;
                rs += p;
            }
        rs += __shfl_xor(rs, 16);
        rs += __shfl_xor(rs, 32);
        l_run = l_run * fsc + rs;
        m_run = mn;
#pragma unroll
        for (int en = 0; en < 4; ++en)
#pragma unroll
            for (int rr = 0; rr < 4; ++rr) {
                oH[en][rr] *= fsc;
                oM[en][rr] *= fsc;
            }

#pragma unroll
        for (int sm = 0; sm < 4; ++sm) {
            half4 ph4, pm4;
#pragma unroll
            for (int rr = 0; rr < 4; ++rr) {
                f16 hh, mm;
                split2h(sv[sm][rr], hh, mm);
                ph4[rr] = hh;
                pm4[rr] = mm;
            }
            int sbase = sm * 16 + (g << 2);
            int sp = (sbase >> 3) ^ (tl & 7);
            int eo = PB + tl * 64 + sp * 8 + (sbase & 7);
            *(half4*)(lds + eo) = ph4;
            *(half4*)(lds + eo + 1024) = pm4;
        }
        asm volatile("s_waitcnt lgkmcnt(0)" ::: "memory");
        __builtin_amdgcn_sched_barrier(0);

        half8 Ph[2], Pm[2];
#pragma unroll
        for (int kf = 0; kf < 2; ++kf) {
            int sp = ((kf * 4 + g) ^ (tl & 7)) << 3;
            Ph[kf] = *(const half8*)(lds + PB + tl * 64 + sp);
            Pm[kf] = *(const half8*)(lds + PB + 1024 + tl * 64 + sp);
        }
#pragma unroll
        for (int en = 0; en < 4; ++en) {
            int el = en * 16 + tl;
#pragma unroll
            for (int kf = 0; kf < 2; ++kf) {
                int sp = ((kf * 4 + g) ^ (el & 7)) << 3;
                half8 vh = *(const half8*)(lds + 8192 + el * 64 + sp);
                half8 vm = *(const half8*)(lds + 12288 + el * 64 + sp);
                oM[en] = __builtin_amdgcn_mfma_f32_16x16x32_f16(vm, Ph[kf], oM[en], 0, 0, 0);
                oM[en] = __builtin_amdgcn_mfma_f32_16x16x32_f16(vh, Pm[kf], oM[en], 0, 0, 0);
                oH[en] = __builtin_amdgcn_mfma_f32_16x16x32_f16(vh, Ph[kf], oH[en], 0, 0, 0);
            }
        }
        __syncthreads();
    }

    float inv = 1.f / l_run;
    size_t obase = (size_t)(b * 512 + t0 + wid * 16 + tl) * 1024 + h * 64;
#pragma unroll
    for (int en = 0; en < 4; ++en) {
        half4 ph4, pm4;
#pragma unroll
        for (int rr = 0; rr < 4; ++rr) {
            float v = (oH[en][rr] + oM[en][rr] * MINV) * inv;
            f16 hh, mm;
            split2h(v, hh, mm);
            ph4[rr] = hh;
            pm4[rr] = mm;
        }
        size_t oc = obase + en * 16 + (g << 2);
        *(half4*)(outp + oc) = ph4;
        *(half4*)(outp + OPS + oc) = pm4;
    }
}

// ---------------------------------------------------------------------------
extern "C" void kernel_launch(void* const* d_in, const int* in_sizes, int n_in,
                              void* d_out, int out_size, void* d_ws, size_t ws_size,
                              hipStream_t stream) {
    const int*   idx = (const int*)  d_in[0];
    const float* tok = (const float*)d_in[1];
    const float* pos = (const float*)d_in[2];
    const float* Wq  = (const float*)d_in[3];
    const float* bq  = (const float*)d_in[4];
    const float* Wk  = (const float*)d_in[5];
    const float* bk  = (const float*)d_in[6];
    const float* Wv  = (const float*)d_in[7];
    const float* bv  = (const float*)d_in[8];
    const float* Wo  = (const float*)d_in[9];
    const float* bo  = (const float*)d_in[10];
    const float* W1  = (const float*)d_in[11];
    const float* b1  = (const float*)d_in[12];
    const float* W2  = (const float*)d_in[13];
    const float* b2  = (const float*)d_in[14];
    const float* nw  = (const float*)d_in[15];
    const float* fnw = (const float*)d_in[16];
    const float* Wf  = (const float*)d_in[17];
    const float* bf  = (const float*)d_in[18];
    float* out = (float*)d_out;

    const size_t SZ   = (size_t)BT * DMODEL;
    const size_t HSZF = (size_t)BT * DFF;
    const size_t QPS  = (size_t)BT * QLD;
    const size_t VPS  = (size_t)BATCH * NHEAD * HSZ * T_SEQ;

    char* w = (char*)d_ws;
    auto alloc = [&](size_t bytes) {
        char* p = w;
        w += (bytes + 255) & ~(size_t)255;
        return p;
    };
    float* x    = (float*)alloc(SZ * 4);
    float* xo   = (float*)alloc(SZ * 4);
    f16*   xnp  = (f16*)  alloc(SZ * 2 * 2);
    f16*   qkvp = (f16*)  alloc(QPS * 2 * 2);
    f16*   vTb  = (f16*)  alloc(VPS * 2 * 2);
    f16*   aop  = (f16*)  alloc(SZ * 2 * 2);
    f16*   hbp  = (f16*)  alloc(HSZF * 2 * 2);
    char*  wreg = alloc(132ull * 1024 * 1024);
    f16*   qkvTp = (f16*)wreg;
    f16*   woTp  = qkvTp + 2ull * QLD * DMODEL;
    f16*   w1Tp  = woTp  + 2ull * DMODEL * DMODEL;
    f16*   w2Tp  = w1Tp  + 2ull * DFF * DMODEL;
    f16*   wfp   = (f16*)wreg;
    float* catb  = (float*)alloc((size_t)NLAYER * QLD * 4);

    cat_bias<<<(NLAYER * QLD) / 256, 256, 0, stream>>>(bq, bk, bv, catb);
    embed_kernel<<<BT, 256, 0, stream>>>(idx, tok, pos, x);

    for (int l = 0; l < NLAYER; ++l) {
        const float* nwl = nw + (size_t)l * DMODEL;
        const float* catbl = catb + (size_t)l * QLD;
        const float* bol = bo + (size_t)l * DMODEL;
        const float* b1l = b1 + (size_t)l * DFF;
        const float* b2l = b2 + (size_t)l * DMODEL;

        {
            long izs = (long)DMODEL * HSZ;
            long ozi = (long)HSZ * DMODEL;
            size_t ps = (size_t)QLD * DMODEL;
            dim3 gq(HSZ / 32, DMODEL / 32, NHEAD);
            const float* Wql = Wq + (size_t)l * NHEAD * DMODEL * HSZ;
            const float* Wkl = Wk + (size_t)l * NHEAD * DMODEL * HSZ;
            const float* Wvl = Wv + (size_t)l * NHEAD * DMODEL * HSZ;
            transpose_split<<<gq, 256, 0, stream>>>(Wql, qkvTp,                 ps, DMODEL, HSZ, izs, ozi);
            transpose_split<<<gq, 256, 0, stream>>>(Wkl, qkvTp + 1024ul * 1024, ps, DMODEL, HSZ, izs, ozi);
            transpose_split<<<gq, 256, 0, stream>>>(Wvl, qkvTp + 2048ul * 1024, ps, DMODEL, HSZ, izs, ozi);
            transpose_split<<<dim3(DMODEL / 32, DMODEL / 32, 1), 256, 0, stream>>>(
                Wo + (size_t)l * DMODEL * DMODEL, woTp, (size_t)DMODEL * DMODEL, DMODEL, DMODEL, 0, 0);
            transpose_split<<<dim3(DFF / 32, DMODEL / 32, 1), 256, 0, stream>>>(
                W1 + (size_t)l * DMODEL * DFF, w1Tp, (size_t)DFF * DMODEL, DMODEL, DFF, 0, 0);
            transpose_split<<<dim3(DMODEL / 32, DFF / 32, 1), 256, 0, stream>>>(
                W2 + (size_t)l * DMODEL * DFF, w2Tp, (size_t)DMODEL * DFF, DFF, DMODEL, 0, 0);
        }

        auto attn = [&](const float* resid, float* outp, int causal) {
            gemm_f16<false, true, true><<<dim3((BT / 128) * (QLD / 128)), 512, 0, stream>>>(
                xnp, SZ, qkvTp, (size_t)QLD * DMODEL, catbl, nullptr,
                nullptr, qkvp, QPS, vTb, VPS, QLD, DMODEL);
            if (causal)
                attn_mfma<1><<<dim3(1024), 256, 0, stream>>>(
                    qkvp, QPS, vTb, VPS, aop, SZ);
            else
                attn_mfma<0><<<dim3(1024), 256, 0, stream>>>(
                    qkvp, QPS, vTb, VPS, aop, SZ);
            gemm_f16<false, false, false><<<dim3((BT / 128) * (DMODEL / 128)), 512, 0, stream>>>(
                aop, SZ, woTp, (size_t)DMODEL * DMODEL, bol, resid,
                outp, nullptr, 0, nullptr, 0, DMODEL, DMODEL);
        };

        // x_out1 = x + attn(rms(x), unmasked)
        rms_split<<<BT, 256, 0, stream>>>(x, nwl, xnp, SZ);
        attn(x, xo, 0);
        // x_out2 = x + ffn(rms(x_out1))      (residual from ORIGINAL x)
        rms_split<<<BT, 256, 0, stream>>>(xo, nwl, xnp, SZ);
        gemm_f16<true, true, false><<<dim3((BT / 128) * (DFF / 128)), 512, 0, stream>>>(
            xnp, SZ, w1Tp, (size_t)DFF * DMODEL, b1l, nullptr,
            nullptr, hbp, HSZF, nullptr, 0, DFF, DMODEL);
        gemm_f16<false, false, false><<<dim3((BT / 128) * (DMODEL / 128)), 512, 0, stream>>>(
            hbp, HSZF, w2Tp, (size_t)DMODEL * DFF, b2l, x,
            xo, nullptr, 0, nullptr, 0, DMODEL, DFF);
        // x = x_out2 + attn(rms(x_out2), masked)
        rms_split<<<BT, 256, 0, stream>>>(xo, nwl, xnp, SZ);
        attn(xo, x, 1);
    }

    // final: logits = rms(x, fnw) @ Wf + bf   (single-pass f16, NT stores)
    rms_split<<<BT, 256, 0, stream>>>(x, fnw, xnp, SZ);
    transpose_split<<<dim3(VOCAB / 32, DMODEL / 32, 1), 256, 0, stream>>>(
        Wf, wfp, (size_t)VOCAB * DMODEL, DMODEL, VOCAB, 0, 0);
    gemm_f16_1p<<<dim3((BT / 128) * (VOCAB / 128)), 512, 0, stream>>>(
        xnp, wfp, bf, out, VOCAB, DMODEL);
}

// Round 19
// 5740.697 us; speedup vs baseline: 1.1071x; 1.0018x over previous
//
#include <hip/hip_runtime.h>
#include <hip/hip_bf16.h>
#include <cstdint>
#include <cstddef>

#define T_SEQ   512
#define BATCH   8
#define BT      4096
#define DMODEL  1024
#define NHEAD   16
#define HSZ     64
#define NLAYER  8
#define DFF     4096
#define VOCAB   32000
#define EPS     1e-6f
#define NEG_SLOPE 0.1f
#define QLD     3072
#define MSCALE  2048.0f
#define MINV    (1.0f / 2048.0f)

typedef _Float16 f16;
typedef __attribute__((ext_vector_type(8))) _Float16 half8;
typedef __attribute__((ext_vector_type(4))) _Float16 half4;
typedef __attribute__((ext_vector_type(4))) float f32x4;

#define AS1 __attribute__((address_space(1)))
#define AS3 __attribute__((address_space(3)))

#define WAIT_BAR(N) asm volatile("s_waitcnt vmcnt(" #N ")\ns_barrier" ::: "memory")
#define LGKM_BAR()  asm volatile("s_waitcnt lgkmcnt(0)\ns_barrier" ::: "memory")

// ---------------------------------------------------------------------------
__global__ void embed_kernel(const int* __restrict__ idx,
                             const float* __restrict__ tok,
                             const float* __restrict__ pos,
                             float* __restrict__ x) {
    int bt  = blockIdx.x;
    int tid = threadIdx.x;
    int token = idx[bt];
    int t = bt & (T_SEQ - 1);
    float4 a = reinterpret_cast<const float4*>(tok + (size_t)token * DMODEL)[tid];
    float4 p = reinterpret_cast<const float4*>(pos + (size_t)t * DMODEL)[tid];
    reinterpret_cast<float4*>(x + (size_t)bt * DMODEL)[tid] =
        make_float4(a.x + p.x, a.y + p.y, a.z + p.z, a.w + p.w);
}

// ---------------------------------------------------------------------------
__device__ __forceinline__ void split2h(float v, f16& h, f16& m) {
    f16 hh = (f16)v;
    float hf = (float)hh;
    if (fabsf(hf) < 6.103515625e-05f) { hh = (f16)0.0f; hf = 0.0f; }
    h = hh;
    m = (f16)((v - hf) * MSCALE);
}

// ---------------------------------------------------------------------------
__global__ void rms_split(const float* __restrict__ x,
                          const float* __restrict__ w,
                          f16* __restrict__ out, size_t planeStride) {
    int row = blockIdx.x;
    int tid = threadIdx.x;
    float4 v = reinterpret_cast<const float4*>(x + (size_t)row * DMODEL)[tid];
    float ss = v.x * v.x + v.y * v.y + v.z * v.z + v.w * v.w;
#pragma unroll
    for (int off = 32; off > 0; off >>= 1) ss += __shfl_xor(ss, off);
    __shared__ float wsum[4];
    if ((tid & 63) == 0) wsum[tid >> 6] = ss;
    __syncthreads();
    float tot = wsum[0] + wsum[1] + wsum[2] + wsum[3];
    float scale = rsqrtf(tot * (1.0f / DMODEL) + EPS);
    float4 wv = reinterpret_cast<const float4*>(w)[tid];
    float o[4] = {v.x * scale * wv.x, v.y * scale * wv.y,
                  v.z * scale * wv.z, v.w * scale * wv.w};
    size_t base = (size_t)row * DMODEL + tid * 4;
#pragma unroll
    for (int j = 0; j < 4; ++j) {
        f16 h, m;
        split2h(o[j], h, m);
        out[base + j] = h;
        out[planeStride + base + j] = m;
    }
}

// ---------------------------------------------------------------------------
__global__ __launch_bounds__(256)
void transpose_split(const float* __restrict__ in, f16* __restrict__ out,
                     size_t planeStride, int R, int C,
                     long izs, long ozi) {
    int z = blockIdx.z;
    in  += (size_t)z * izs;
    out += (size_t)z * ozi;
    __shared__ float tile[32][33];
    int r0 = blockIdx.y << 5, c0 = blockIdx.x << 5;
    int tx = threadIdx.x & 31, ty = threadIdx.x >> 5;
#pragma unroll
    for (int i = 0; i < 4; ++i) {
        int r = ty + (i << 3);
        tile[r][tx] = in[(size_t)(r0 + r) * C + c0 + tx];
    }
    __syncthreads();
#pragma unroll
    for (int i = 0; i < 4; ++i) {
        int c = ty + (i << 3);
        float v = tile[tx][c];
        size_t o = (size_t)(c0 + c) * R + r0 + tx;
        f16 h, m;
        split2h(v, h, m);
        out[o] = h;
        out[planeStride + o] = m;
    }
}

// concat per-layer qkv bias into (L, 3072) f32
__global__ void cat_bias(const float* __restrict__ bq, const float* __restrict__ bk,
                         const float* __restrict__ bv, float* __restrict__ cb) {
    int i = blockIdx.x * 256 + threadIdx.x;
    int l = i / QLD, r = i - l * QLD;
    const float* src = (r < 1024) ? bq : ((r < 2048) ? bk : bv);
    cb[i] = src[l * 1024 + (r & 1023)];
}

// ---------------------------------------------------------------------------
// f16 split-GEMM (r18's best-measured schedule, canary-validated):
// full dbuf both operands, 2 barriers/step, spread staging (A top / B mid).
template <bool LRELU, bool SPLITOUT, bool VOUT>
__global__ __launch_bounds__(512, 4)
void gemm_f16(const f16* __restrict__ A, size_t aPS,
              const f16* __restrict__ Bt, size_t bPS,
              const float* __restrict__ bias,
              const float* __restrict__ resid,
              float* __restrict__ C, f16* __restrict__ Cp, size_t cPS,
              f16* __restrict__ vTp, size_t vPS,
              int N, int K) {
    __shared__ f16 As[2][2 * 4096];
    __shared__ f16 Bs[2][2 * 4096];

    int chunk = gridDim.x >> 3;
    int bid = blockIdx.x;
    int sw = (bid & 7) * chunk + (bid >> 3);
    int m0 = (sw & 31) << 7;
    int n0 = (sw >> 5) << 7;

    const int tid  = threadIdx.x;
    const int lane = tid & 63;
    const int wid  = tid >> 6;

    const int ssk = (((tid & 3) ^ ((tid >> 3) & 3)) << 3);
    const size_t offA = (size_t)(m0 + (tid >> 2)) * K + ssk;
    const size_t offB = (size_t)(n0 + (tid >> 2)) * K + ssk;
    const int ldst = wid * 512;

    f32x4 accH[4][2], accM[4][2];
#pragma unroll
    for (int i = 0; i < 4; ++i)
#pragma unroll
        for (int j = 0; j < 2; ++j) {
            accH[i][j] = (f32x4){0.f, 0.f, 0.f, 0.f};
            accM[i][j] = (f32x4){0.f, 0.f, 0.f, 0.f};
        }

    const int wr = wid >> 2, wc = wid & 3;
    const int fm = lane & 15;
    const int rslot = (((lane >> 4) ^ ((lane >> 1) & 3)) & 3) << 3;
    const int foffA0 = (wr * 64 + fm) * 32 + rslot;
    const int foffB0 = (wc * 32 + fm) * 32 + rslot;

    auto STAGE_A = [&](int buf, int k0) {
#pragma unroll
        for (int pp = 0; pp < 2; ++pp)
            __builtin_amdgcn_global_load_lds(
                (const AS1 void*)(A + pp * aPS + offA + k0),
                (AS3 void*)(&As[buf][pp * 4096 + ldst]), 16, 0, 0);
    };
    auto STAGE_B = [&](int buf, int k0) {
#pragma unroll
        for (int pp = 0; pp < 2; ++pp)
            __builtin_amdgcn_global_load_lds(
                (const AS1 void*)(Bt + pp * bPS + offB + k0),
                (AS3 void*)(&Bs[buf][pp * 4096 + ldst]), 16, 0, 0);
    };

    const int nt = K >> 5;
    STAGE_A(0, 0);
    STAGE_B(0, 0);
    int cur = 0;
    for (int t = 0; t < nt; ++t) {
        if (t + 1 < nt) {
            STAGE_A(cur ^ 1, (t + 1) << 5);
            WAIT_BAR(2);
        } else {
            WAIT_BAR(0);
        }

        half8 bh[2], bm[2];
#pragma unroll
        for (int j = 0; j < 2; ++j) {
            bh[j] = *(const half8*)(&Bs[cur][foffB0 + j * 512]);
            bm[j] = *(const half8*)(&Bs[cur][4096 + foffB0 + j * 512]);
        }
        if (t + 1 < nt) STAGE_B(cur ^ 1, (t + 1) << 5);

#pragma unroll
        for (int i = 0; i < 4; ++i) {
            half8 ah = *(const half8*)(&As[cur][foffA0 + i * 512]);
            half8 am = *(const half8*)(&As[cur][4096 + foffA0 + i * 512]);
#pragma unroll
            for (int j = 0; j < 2; ++j) {
                accM[i][j] = __builtin_amdgcn_mfma_f32_16x16x32_f16(
                    am, bh[j], accM[i][j], 0, 0, 0);
                accM[i][j] = __builtin_amdgcn_mfma_f32_16x16x32_f16(
                    ah, bm[j], accM[i][j], 0, 0, 0);
                accH[i][j] = __builtin_amdgcn_mfma_f32_16x16x32_f16(
                    ah, bh[j], accH[i][j], 0, 0, 0);
            }
        }
        LGKM_BAR();
        cur ^= 1;
    }

    const bool vblock = VOUT && (n0 >= 2048);
#pragma unroll
    for (int i = 0; i < 4; ++i) {
        int mbase = m0 + wr * 64 + i * 16 + ((lane >> 4) << 2);
#pragma unroll
        for (int j = 0; j < 2; ++j) {
            int n = n0 + wc * 32 + j * 16 + fm;
            float bv = bias[n];
            if (vblock) {
                half4 ph4, pm4;
#pragma unroll
                for (int rr = 0; rr < 4; ++rr) {
                    float v = accH[i][j][rr] + accM[i][j][rr] * MINV + bv;
                    f16 hh, mm;
                    split2h(v, hh, mm);
                    ph4[rr] = hh;
                    pm4[rr] = mm;
                }
                int nn = n - 2048;
                int bb = mbase >> 9, tt = mbase & 511;
                size_t vo = (((size_t)(bb * 16 + (nn >> 6)) * 64 + (nn & 63)) << 9) + tt;
                *(half4*)(vTp + vo) = ph4;
                *(half4*)(vTp + vPS + vo) = pm4;
            } else {
#pragma unroll
                for (int rr = 0; rr < 4; ++rr) {
                    int m = mbase + rr;
                    float v = accH[i][j][rr] + accM[i][j][rr] * MINV + bv;
                    if (LRELU) v = (v >= 0.f) ? v : NEG_SLOPE * v;
                    size_t o = (size_t)m * N + n;
                    if (SPLITOUT) {
                        f16 h, mm;
                        split2h(v, h, mm);
                        Cp[o] = h;
                        Cp[cPS + o] = mm;
                    } else {
                        if (resid) v += resid[o];
                        C[o] = v;
                    }
                }
            }
        }
    }
}

// ---------------------------------------------------------------------------
// Single-pass plain-f16 vocab GEMM; r19: spread staging (A top with
// WAIT_BAR(1), B mid-body into the other buffer), 2 barriers/step, NT stores.
// vmcnt FIFO: top outstanding A(t):1+B(t):1; issue A(t+1):1; WAIT_BAR(1)
// drains A(t),B(t), keeps A(t+1) in flight.
__global__ __launch_bounds__(512, 4)
void gemm_f16_1p(const f16* __restrict__ A,
                 const f16* __restrict__ Bt,
                 const float* __restrict__ bias,
                 float* __restrict__ C, int N, int K) {
    __shared__ f16 As[2][4096];
    __shared__ f16 Bs[2][4096];

    int chunk = gridDim.x >> 3;
    int bid = blockIdx.x;
    int sw = (bid & 7) * chunk + (bid >> 3);
    int m0 = (sw & 31) << 7;
    int n0 = (sw >> 5) << 7;

    const int tid  = threadIdx.x;
    const int lane = tid & 63;
    const int wid  = tid >> 6;

    const int ssk = (((tid & 3) ^ ((tid >> 3) & 3)) << 3);
    const size_t offA = (size_t)(m0 + (tid >> 2)) * K + ssk;
    const size_t offB = (size_t)(n0 + (tid >> 2)) * K + ssk;
    const int ldst = wid * 512;

    f32x4 acc[4][2];
#pragma unroll
    for (int i = 0; i < 4; ++i)
#pragma unroll
        for (int j = 0; j < 2; ++j) acc[i][j] = (f32x4){0.f, 0.f, 0.f, 0.f};

    const int wr = wid >> 2, wc = wid & 3;
    const int fm = lane & 15;
    const int rslot = (((lane >> 4) ^ ((lane >> 1) & 3)) & 3) << 3;
    const int foffA0 = (wr * 64 + fm) * 32 + rslot;
    const int foffB0 = (wc * 32 + fm) * 32 + rslot;

    auto STAGE_A = [&](int buf, int k0) {
        __builtin_amdgcn_global_load_lds((const AS1 void*)(A + offA + k0),
                                         (AS3 void*)(&As[buf][ldst]), 16, 0, 0);
    };
    auto STAGE_B = [&](int buf, int k0) {
        __builtin_amdgcn_global_load_lds((const AS1 void*)(Bt + offB + k0),
                                         (AS3 void*)(&Bs[buf][ldst]), 16, 0, 0);
    };

    const int nt = K >> 5;
    STAGE_A(0, 0);
    STAGE_B(0, 0);
    int cur = 0;
    for (int t = 0; t < nt; ++t) {
        if (t + 1 < nt) {
            STAGE_A(cur ^ 1, (t + 1) << 5);
            WAIT_BAR(1);
        } else {
            WAIT_BAR(0);
        }

        half8 bh[2];
#pragma unroll
        for (int j = 0; j < 2; ++j)
            bh[j] = *(const half8*)(&Bs[cur][foffB0 + j * 512]);
        if (t + 1 < nt) STAGE_B(cur ^ 1, (t + 1) << 5);

#pragma unroll
        for (int i = 0; i < 4; ++i) {
            half8 ah = *(const half8*)(&As[cur][foffA0 + i * 512]);
#pragma unroll
            for (int j = 0; j < 2; ++j)
                acc[i][j] = __builtin_amdgcn_mfma_f32_16x16x32_f16(
                    ah, bh[j], acc[i][j], 0, 0, 0);
        }
        LGKM_BAR();
        cur ^= 1;
    }

#pragma unroll
    for (int i = 0; i < 4; ++i) {
        int mbase = m0 + wr * 64 + i * 16 + ((lane >> 4) << 2);
#pragma unroll
        for (int j = 0; j < 2; ++j) {
            int n = n0 + wc * 32 + j * 16 + fm;
            float bv = bias[n];
#pragma unroll
            for (int rr = 0; rr < 4; ++rr) {
                int m = mbase + rr;
                __builtin_nontemporal_store(acc[i][j][rr] + bv,
                                            C + (size_t)m * N + n);
            }
        }
    }
}

// ---------------------------------------------------------------------------
// MFMA flash attention, split-f16 3-pass, XCD-affinity grid.
// r19: s_setprio(1) around the MFMA clusters (T5 -- measured +4-7% on attn
// structures with wave role diversity; numerics untouched).
template <int CAUSAL>
__global__ __launch_bounds__(256)
void attn_mfma(const f16* __restrict__ qkvp, size_t QPS,
               const f16* __restrict__ vT, size_t VPS,
               f16* __restrict__ outp, size_t OPS) {
    __shared__ f16 lds[24576];
    const int tid  = threadIdx.x;
    const int lane = tid & 63;
    const int wid  = tid >> 6;
    const int tl   = lane & 15;
    const int g    = lane >> 4;

    int bid = blockIdx.x;
    int sw = ((bid & 7) << 7) + (bid >> 3);
    int bh = sw >> 3;
    int qt = sw & 7;
    int b = bh >> 4, h = bh & 15;
    int t0 = qt << 6;
    const int PB = 16384 + wid * 2048;

    half8 Qh[2], Qm[2];
    {
        const f16* qb = qkvp + (size_t)(b * 512 + t0 + wid * 16 + tl) * 3072
                        + h * 64 + (g << 3);
        Qh[0] = *(const half8*)(qb);
        Qh[1] = *(const half8*)(qb + 32);
        Qm[0] = *(const half8*)(qb + QPS);
        Qm[1] = *(const half8*)(qb + QPS + 32);
    }

    f32x4 oH[4], oM[4];
#pragma unroll
    for (int en = 0; en < 4; ++en) {
        oH[en] = (f32x4){0.f, 0.f, 0.f, 0.f};
        oM[en] = (f32x4){0.f, 0.f, 0.f, 0.f};
    }
    float m_run = -INFINITY, l_run = 0.f;

    auto STAGE1 = [&](int ldsOff, const f16* srcBase, int rowStride) {
#pragma unroll
        for (int it = 0; it < 2; ++it) {
            int r  = (tid >> 3) + it * 32;
            int cp = (tid & 7) ^ (r & 7);
            __builtin_amdgcn_global_load_lds(
                (const AS1 void*)(srcBase + (size_t)r * rowStride + cp * 8),
                (AS3 void*)(lds + ldsOff + (it * 32 + wid * 8) * 64), 16, 0, 0);
        }
    };

    const int NT = CAUSAL ? (qt + 1) : (T_SEQ / 64);
    for (int st = 0; st < NT; ++st) {
        int s0 = st << 6;
        {
            const f16* kS = qkvp + (size_t)(b * 512 + s0) * 3072 + 1024 + h * 64;
            const f16* vS = vT + ((size_t)(bh * 64) << 9) + s0;
            STAGE1(0,     kS, 3072);
            STAGE1(4096,  kS + QPS, 3072);
            STAGE1(8192,  vS, 512);
            STAGE1(12288, vS + VPS, 512);
        }
        __syncthreads();

        f32x4 sH[4], sM[4];
#pragma unroll
        for (int sm = 0; sm < 4; ++sm) {
            sH[sm] = (f32x4){0.f, 0.f, 0.f, 0.f};
            sM[sm] = (f32x4){0.f, 0.f, 0.f, 0.f};
        }
        __builtin_amdgcn_s_setprio(1);
#pragma unroll
        for (int sm = 0; sm < 4; ++sm) {
            int sl = sm * 16 + tl;
#pragma unroll
            for (int kf = 0; kf < 2; ++kf) {
                int sp = ((kf * 4 + g) ^ (sl & 7)) << 3;
                half8 kh = *(const half8*)(lds + sl * 64 + sp);
                half8 km = *(const half8*)(lds + 4096 + sl * 64 + sp);
                sM[sm] = __builtin_amdgcn_mfma_f32_16x16x32_f16(km, Qh[kf], sM[sm], 0, 0, 0);
                sM[sm] = __builtin_amdgcn_mfma_f32_16x16x32_f16(kh, Qm[kf], sM[sm], 0, 0, 0);
                sH[sm] = __builtin_amdgcn_mfma_f32_16x16x32_f16(kh, Qh[kf], sH[sm], 0, 0, 0);
            }
        }
        __builtin_amdgcn_s_setprio(0);

        float sv[4][4];
#pragma unroll
        for (int sm = 0; sm < 4; ++sm)
#pragma unroll
            for (int rr = 0; rr < 4; ++rr) {
                float v = (sH[sm][rr] + sM[sm][rr] * MINV) * 8.0f;
                if (CAUSAL && st == NT - 1) {
                    int sg = s0 + sm * 16 + (g << 2) + rr;
                    int tg = t0 + wid * 16 + tl;
                    if (sg > tg) v = -INFINITY;
                }
                sv[sm][rr] = v;
            }
        float rmax = -INFINITY;
#pragma unroll
        for (int sm = 0; sm < 4; ++sm)
#pragma unroll
            for (int rr = 0; rr < 4; ++rr) rmax = fmaxf(rmax, sv[sm][rr]);
        rmax = fmaxf(rmax, __shfl_xor(rmax, 16));
        rmax = fmaxf(rmax, __shfl_xor(rmax, 32));
        float mn = fmaxf(m_run, rmax);
        float fsc = __expf(m_run - mn);
        float rs = 0.f;
#pragma unroll
        for (int sm = 0; sm < 4; ++sm)
#pragma unroll
            for (int rr = 0; rr < 4; ++rr) {
                float p = __expf(sv[sm][rr] - mn);
                sv[sm][rr] = p;
                rs += p;
            }
        rs += __shfl_xor(rs, 16);
        rs += __shfl_xor(rs, 32);
        l_run = l_run * fsc + rs;
        m_run = mn;
#pragma unroll
        for (int en = 0; en < 4; ++en)
#pragma unroll
            for (int rr = 0; rr < 4; ++rr) {
                oH[en][rr] *= fsc;
                oM[en][rr] *= fsc;
            }

#pragma unroll
        for (int sm = 0; sm < 4; ++sm) {
            half4 ph4, pm4;
#pragma unroll
            for (int rr = 0; rr < 4; ++rr) {
                f16 hh, mm;
                split2h(sv[sm][rr], hh, mm);
                ph4[rr] = hh;
                pm4[rr] = mm;
            }
            int sbase = sm * 16 + (g << 2);
            int sp = (sbase >> 3) ^ (tl & 7);
            int eo = PB + tl * 64 + sp * 8 + (sbase & 7);
            *(half4*)(lds + eo) = ph4;
            *(half4*)(lds + eo + 1024) = pm4;
        }
        asm volatile("s_waitcnt lgkmcnt(0)" ::: "memory");
        __builtin_amdgcn_sched_barrier(0);

        half8 Ph[2], Pm[2];
#pragma unroll
        for (int kf = 0; kf < 2; ++kf) {
            int sp = ((kf * 4 + g) ^ (tl & 7)) << 3;
            Ph[kf] = *(const half8*)(lds + PB + tl * 64 + sp);
            Pm[kf] = *(const half8*)(lds + PB + 1024 + tl * 64 + sp);
        }
        __builtin_amdgcn_s_setprio(1);
#pragma unroll
        for (int en = 0; en < 4; ++en) {
            int el = en * 16 + tl;
#pragma unroll
            for (int kf = 0; kf < 2; ++kf) {
                int sp = ((kf * 4 + g) ^ (el & 7)) << 3;
                half8 vh = *(const half8*)(lds + 8192 + el * 64 + sp);
                half8 vm = *(const half8*)(lds + 12288 + el * 64 + sp);
                oM[en] = __builtin_amdgcn_mfma_f32_16x16x32_f16(vm, Ph[kf], oM[en], 0, 0, 0);
                oM[en] = __builtin_amdgcn_mfma_f32_16x16x32_f16(vh, Pm[kf], oM[en], 0, 0, 0);
                oH[en] = __builtin_amdgcn_mfma_f32_16x16x32_f16(vh, Ph[kf], oH[en], 0, 0, 0);
            }
        }
        __builtin_amdgcn_s_setprio(0);
        __syncthreads();
    }

    float inv = 1.f / l_run;
    size_t obase = (size_t)(b * 512 + t0 + wid * 16 + tl) * 1024 + h * 64;
#pragma unroll
    for (int en = 0; en < 4; ++en) {
        half4 ph4, pm4;
#pragma unroll
        for (int rr = 0; rr < 4; ++rr) {
            float v = (oH[en][rr] + oM[en][rr] * MINV) * inv;
            f16 hh, mm;
            split2h(v, hh, mm);
            ph4[rr] = hh;
            pm4[rr] = mm;
        }
        size_t oc = obase + en * 16 + (g << 2);
        *(half4*)(outp + oc) = ph4;
        *(half4*)(outp + OPS + oc) = pm4;
    }
}

// ---------------------------------------------------------------------------
extern "C" void kernel_launch(void* const* d_in, const int* in_sizes, int n_in,
                              void* d_out, int out_size, void* d_ws, size_t ws_size,
                              hipStream_t stream) {
    const int*   idx = (const int*)  d_in[0];
    const float* tok = (const float*)d_in[1];
    const float* pos = (const float*)d_in[2];
    const float* Wq  = (const float*)d_in[3];
    const float* bq  = (const float*)d_in[4];
    const float* Wk  = (const float*)d_in[5];
    const float* bk  = (const float*)d_in[6];
    const float* Wv  = (const float*)d_in[7];
    const float* bv  = (const float*)d_in[8];
    const float* Wo  = (const float*)d_in[9];
    const float* bo  = (const float*)d_in[10];
    const float* W1  = (const float*)d_in[11];
    const float* b1  = (const float*)d_in[12];
    const float* W2  = (const float*)d_in[13];
    const float* b2  = (const float*)d_in[14];
    const float* nw  = (const float*)d_in[15];
    const float* fnw = (const float*)d_in[16];
    const float* Wf  = (const float*)d_in[17];
    const float* bf  = (const float*)d_in[18];
    float* out = (float*)d_out;

    const size_t SZ   = (size_t)BT * DMODEL;
    const size_t HSZF = (size_t)BT * DFF;
    const size_t QPS  = (size_t)BT * QLD;
    const size_t VPS  = (size_t)BATCH * NHEAD * HSZ * T_SEQ;

    char* w = (char*)d_ws;
    auto alloc = [&](size_t bytes) {
        char* p = w;
        w += (bytes + 255) & ~(size_t)255;
        return p;
    };
    float* x    = (float*)alloc(SZ * 4);
    float* xo   = (float*)alloc(SZ * 4);
    f16*   xnp  = (f16*)  alloc(SZ * 2 * 2);
    f16*   qkvp = (f16*)  alloc(QPS * 2 * 2);
    f16*   vTb  = (f16*)  alloc(VPS * 2 * 2);
    f16*   aop  = (f16*)  alloc(SZ * 2 * 2);
    f16*   hbp  = (f16*)  alloc(HSZF * 2 * 2);
    char*  wreg = alloc(132ull * 1024 * 1024);
    f16*   qkvTp = (f16*)wreg;
    f16*   woTp  = qkvTp + 2ull * QLD * DMODEL;
    f16*   w1Tp  = woTp  + 2ull * DMODEL * DMODEL;
    f16*   w2Tp  = w1Tp  + 2ull * DFF * DMODEL;
    f16*   wfp   = (f16*)wreg;
    float* catb  = (float*)alloc((size_t)NLAYER * QLD * 4);

    cat_bias<<<(NLAYER * QLD) / 256, 256, 0, stream>>>(bq, bk, bv, catb);
    embed_kernel<<<BT, 256, 0, stream>>>(idx, tok, pos, x);

    for (int l = 0; l < NLAYER; ++l) {
        const float* nwl = nw + (size_t)l * DMODEL;
        const float* catbl = catb + (size_t)l * QLD;
        const float* bol = bo + (size_t)l * DMODEL;
        const float* b1l = b1 + (size_t)l * DFF;
        const float* b2l = b2 + (size_t)l * DMODEL;

        {
            long izs = (long)DMODEL * HSZ;
            long ozi = (long)HSZ * DMODEL;
            size_t ps = (size_t)QLD * DMODEL;
            dim3 gq(HSZ / 32, DMODEL / 32, NHEAD);
            const float* Wql = Wq + (size_t)l * NHEAD * DMODEL * HSZ;
            const float* Wkl = Wk + (size_t)l * NHEAD * DMODEL * HSZ;
            const float* Wvl = Wv + (size_t)l * NHEAD * DMODEL * HSZ;
            transpose_split<<<gq, 256, 0, stream>>>(Wql, qkvTp,                 ps, DMODEL, HSZ, izs, ozi);
            transpose_split<<<gq, 256, 0, stream>>>(Wkl, qkvTp + 1024ul * 1024, ps, DMODEL, HSZ, izs, ozi);
            transpose_split<<<gq, 256, 0, stream>>>(Wvl, qkvTp + 2048ul * 1024, ps, DMODEL, HSZ, izs, ozi);
            transpose_split<<<dim3(DMODEL / 32, DMODEL / 32, 1), 256, 0, stream>>>(
                Wo + (size_t)l * DMODEL * DMODEL, woTp, (size_t)DMODEL * DMODEL, DMODEL, DMODEL, 0, 0);
            transpose_split<<<dim3(DFF / 32, DMODEL / 32, 1), 256, 0, stream>>>(
                W1 + (size_t)l * DMODEL * DFF, w1Tp, (size_t)DFF * DMODEL, DMODEL, DFF, 0, 0);
            transpose_split<<<dim3(DMODEL / 32, DFF / 32, 1), 256, 0, stream>>>(
                W2 + (size_t)l * DMODEL * DFF, w2Tp, (size_t)DMODEL * DFF, DFF, DMODEL, 0, 0);
        }

        auto attn = [&](const float* resid, float* outp, int causal) {
            gemm_f16<false, true, true><<<dim3((BT / 128) * (QLD / 128)), 512, 0, stream>>>(
                xnp, SZ, qkvTp, (size_t)QLD * DMODEL, catbl, nullptr,
                nullptr, qkvp, QPS, vTb, VPS, QLD, DMODEL);
            if (causal)
                attn_mfma<1><<<dim3(1024), 256, 0, stream>>>(
                    qkvp, QPS, vTb, VPS, aop, SZ);
            else
                attn_mfma<0><<<dim3(1024), 256, 0, stream>>>(
                    qkvp, QPS, vTb, VPS, aop, SZ);
            gemm_f16<false, false, false><<<dim3((BT / 128) * (DMODEL / 128)), 512, 0, stream>>>(
                aop, SZ, woTp, (size_t)DMODEL * DMODEL, bol, resid,
                outp, nullptr, 0, nullptr, 0, DMODEL, DMODEL);
        };

        // x_out1 = x + attn(rms(x), unmasked)
        rms_split<<<BT, 256, 0, stream>>>(x, nwl, xnp, SZ);
        attn(x, xo, 0);
        // x_out2 = x + ffn(rms(x_out1))      (residual from ORIGINAL x)
        rms_split<<<BT, 256, 0, stream>>>(xo, nwl, xnp, SZ);
        gemm_f16<true, true, false><<<dim3((BT / 128) * (DFF / 128)), 512, 0, stream>>>(
            xnp, SZ, w1Tp, (size_t)DFF * DMODEL, b1l, nullptr,
            nullptr, hbp, HSZF, nullptr, 0, DFF, DMODEL);
        gemm_f16<false, false, false><<<dim3((BT / 128) * (DMODEL / 128)), 512, 0, stream>>>(
            hbp, HSZF, w2Tp, (size_t)DMODEL * DFF, b2l, x,
            xo, nullptr, 0, nullptr, 0, DMODEL, DFF);
        // x = x_out2 + attn(rms(x_out2), masked)
        rms_split<<<BT, 256, 0, stream>>>(xo, nwl, xnp, SZ);
        attn(xo, x, 1);
    }

    // final: logits = rms(x, fnw) @ Wf + bf   (single-pass f16, NT stores)
    rms_split<<<BT, 256, 0, stream>>>(x, fnw, xnp, SZ);
    transpose_split<<<dim3(VOCAB / 32, DMODEL / 32, 1), 256, 0, stream>>>(
        Wf, wfp, (size_t)VOCAB * DMODEL, DMODEL, VOCAB, 0, 0);
    gemm_f16_1p<<<dim3((BT / 128) * (VOCAB / 128)), 512, 0, stream>>>(
        xnp, wfp, bf, out, VOCAB, DMODEL);
}